// Round 15
// baseline (476.039 us; speedup 1.0000x reference)
//
#include <hip/hip_runtime.h>

// Problem constants
#define NMAT 50
#define BATCH 128
#define FDIM 1024
#define HDIM 4096
#define ROWS 6400            // BATCH*NMAT
#define PSIZE 320000         // BATCH*NMAT*NMAT
#define NPART 16             // split-K partials for gemm2
#define HINF 1e18

// ws layout (bytes):
//   Mpart : fp32 [16][6400][50] split-K partials (20.48 MB)
//   Xh/Xl : packed split-bf16 X     [50 mt][32 k0b][4 kg][128 m][8] 13.1 MB each
//   W1h/l : packed split-bf16 W1^T  [32 nt][32 k0b][4 kg][128 n][8] 8.39 MB each
//   W2h/l : bf16 W2^T planes [64][4096] (cols>=50 zero), 512 KB each, L2-resident
//   hbuf  : u32 hT-packed [4096][max_rows]: (bf16hi<<16)|bf16lo of h^T
#define WS_M_OFF   0
#define WS_XH_OFF  20480000LL
#define WS_XL_OFF  33587200LL
#define WS_W1H_OFF 46694400LL
#define WS_W1L_OFF 55083008LL
#define WS_W2H_OFF 63471616LL
#define WS_W2L_OFF 63995904LL
#define WS_H_OFF   64520192LL
#define WS_MIN     (WS_H_OFF + 128LL * HDIM * 4)   // ~66.6 MB

typedef __bf16 bf16x8 __attribute__((ext_vector_type(8)));
typedef short short8 __attribute__((ext_vector_type(8)));
typedef float f32x4 __attribute__((ext_vector_type(4)));
typedef unsigned short u16;
typedef unsigned int u32;

__device__ __forceinline__ float bf16_to_f32(unsigned short h) {
  return __uint_as_float(((unsigned int)h) << 16);
}
__device__ __forceinline__ unsigned short f32_to_bf16(float f) {
  unsigned int u = __float_as_uint(f);
  u += 0x7FFFu + ((u >> 16) & 1u);   // RNE
  return (unsigned short)(u >> 16);
}

// async global->LDS, 16B per lane; LDS dest = wave-uniform base + lane*16
__device__ __forceinline__ void gload16(const u16* g, u16* l) {
  __builtin_amdgcn_global_load_lds(
      (const __attribute__((address_space(1))) unsigned int*)g,
      (__attribute__((address_space(3))) unsigned int*)l, 16, 0, 0);
}

// ---- wave-wide fp64 min via DPP (round-5..14 verified) ----
__device__ __forceinline__ double wave_min_f64(double x) {
  union { double d; int i[2]; } u, t;
  u.d = x;
#define DPP_MIN_STEP(ctrl)                                                   \
  t.i[0] = __builtin_amdgcn_update_dpp(u.i[0], u.i[0], ctrl, 0xf, 0xf, false);\
  t.i[1] = __builtin_amdgcn_update_dpp(u.i[1], u.i[1], ctrl, 0xf, 0xf, false);\
  u.d = fmin(u.d, t.d);
  DPP_MIN_STEP(0x111)  // row_shr:1
  DPP_MIN_STEP(0x112)  // row_shr:2
  DPP_MIN_STEP(0x114)  // row_shr:4
  DPP_MIN_STEP(0x118)  // row_shr:8
  DPP_MIN_STEP(0x142)  // row_bcast15
  DPP_MIN_STEP(0x143)  // row_bcast31
#undef DPP_MIN_STEP
  union { double d; int i[2]; } r;
  r.i[0] = __builtin_amdgcn_readlane(u.i[0], 63);
  r.i[1] = __builtin_amdgcn_readlane(u.i[1], 63);
  return r.d;
}

// ---- wave-wide fp32 min via DPP (round-14 verified) ----
__device__ __forceinline__ float wave_min_f32(float x) {
  float t;
#define DPP_MINF_STEP(ctrl)                                                  \
  t = __uint_as_float(__builtin_amdgcn_update_dpp(                           \
      (int)__float_as_uint(x), (int)__float_as_uint(x), ctrl, 0xf, 0xf, false));\
  x = fminf(x, t);
  DPP_MINF_STEP(0x111)
  DPP_MINF_STEP(0x112)
  DPP_MINF_STEP(0x114)
  DPP_MINF_STEP(0x118)
  DPP_MINF_STEP(0x142)
  DPP_MINF_STEP(0x143)
#undef DPP_MINF_STEP
  return __uint_as_float(__builtin_amdgcn_readlane((int)__float_as_uint(x), 63));
}

// ---- f64 broadcast-read of one lane's value (uniform index) ----
__device__ __forceinline__ double readlane_f64(double x, int l) {
  union { double d; int i2[2]; } a, b;
  a.d = x;
  b.i2[0] = __builtin_amdgcn_readlane(a.i2[0], l);
  b.i2[1] = __builtin_amdgcn_readlane(a.i2[1], l);
  return b.d;
}

// ---------------- pre-pass: X fp32 -> packed split-bf16 ---------------------
__global__ __launch_bounds__(256) void convert_x(
    const float* __restrict__ X, u16* __restrict__ Xh, u16* __restrict__ Xl) {
  int t = threadIdx.x;
  int mt = blockIdx.x >> 5, k0b = blockIdx.x & 31;
  size_t outbase = (size_t)blockIdx.x * 4096;
#pragma unroll
  for (int it = 0; it < 2; ++it) {
    int idx = t + it * 256;
    int m = idx & 127, kg = idx >> 7;
    const float* src = X + (size_t)(mt * 128 + m) * FDIM + k0b * 32 + kg * 8;
    float4 v0 = *(const float4*)src;
    float4 v1 = *(const float4*)(src + 4);
    float f[8] = {v0.x, v0.y, v0.z, v0.w, v1.x, v1.y, v1.z, v1.w};
    unsigned short h[8], l[8];
#pragma unroll
    for (int j = 0; j < 8; ++j) {
      h[j] = f32_to_bf16(f[j]);
      l[j] = f32_to_bf16(f[j] - bf16_to_f32(h[j]));
    }
    uint4 hv, lv;
    hv.x = h[0] | ((unsigned)h[1] << 16); hv.y = h[2] | ((unsigned)h[3] << 16);
    hv.z = h[4] | ((unsigned)h[5] << 16); hv.w = h[6] | ((unsigned)h[7] << 16);
    lv.x = l[0] | ((unsigned)l[1] << 16); lv.y = l[2] | ((unsigned)l[3] << 16);
    lv.z = l[4] | ((unsigned)l[5] << 16); lv.w = l[6] | ((unsigned)l[7] << 16);
    size_t off = outbase + (size_t)(kg * 128 + m) * 8;
    *(uint4*)&Xh[off] = hv;
    *(uint4*)&Xl[off] = lv;
  }
}

// ---------------- pre-pass: W1 fp32 -> transposed packed split-bf16 ---------
__global__ __launch_bounds__(256) void convert_w1(
    const float* __restrict__ W1, u16* __restrict__ Wh, u16* __restrict__ Wl) {
  int t = threadIdx.x;
  int nt = blockIdx.x >> 5, k0b = blockIdx.x & 31;
  size_t outbase = (size_t)blockIdx.x * 4096;
#pragma unroll
  for (int it = 0; it < 2; ++it) {
    int idx = t + it * 256;
    int n = idx & 127, kg = idx >> 7;
    float f[8];
#pragma unroll
    for (int j = 0; j < 8; ++j)
      f[j] = W1[(size_t)(k0b * 32 + kg * 8 + j) * HDIM + nt * 128 + n];
    unsigned short h[8], l[8];
#pragma unroll
    for (int j = 0; j < 8; ++j) {
      h[j] = f32_to_bf16(f[j]);
      l[j] = f32_to_bf16(f[j] - bf16_to_f32(h[j]));
    }
    uint4 hv, lv;
    hv.x = h[0] | ((unsigned)h[1] << 16); hv.y = h[2] | ((unsigned)h[3] << 16);
    hv.z = h[4] | ((unsigned)h[5] << 16); hv.w = h[6] | ((unsigned)h[7] << 16);
    lv.x = l[0] | ((unsigned)l[1] << 16); lv.y = l[2] | ((unsigned)l[3] << 16);
    lv.z = l[4] | ((unsigned)l[5] << 16); lv.w = l[6] | ((unsigned)l[7] << 16);
    size_t off = outbase + (size_t)(kg * 128 + n) * 8;
    *(uint4*)&Wh[off] = hv;
    *(uint4*)&Wl[off] = lv;
  }
}

// ---------------- pre-pass: W2 fp32 -> transposed split-bf16 planes ---------
__global__ __launch_bounds__(256) void convert_w2(
    const float* __restrict__ W2, u16* __restrict__ W2h, u16* __restrict__ W2l) {
  int idx = blockIdx.x * 256 + threadIdx.x;   // grid 1024 -> 64*4096 elems
  int n = idx >> 12, k = idx & 4095;
  float f = (n < NMAT) ? W2[(size_t)k * NMAT + n] : 0.0f;
  unsigned short hi = f32_to_bf16(f);
  unsigned short lo = f32_to_bf16(f - bf16_to_f32(hi));
  W2h[idx] = hi;
  W2l[idx] = lo;
}

// ---------------- GEMM1 (split-bf16 MFMA): h = leaky(x @ W1 + b1) -----------
// 128x128 tile, BK=32, 4 waves, 48 MFMA per k-step; staging via
// global_load_lds width-16 only. Epilogue: TRANSPOSED uint4 stores
// (hT[col][row]) — round-12 version restored: round-13/14's row-major scalar
// stores cost +15 us and +20% WRITE_SIZE (partial-line write amplification).
__global__ __launch_bounds__(256) void gemm1_mfma(
    const u16* __restrict__ Ah_, const u16* __restrict__ Al_,
    const u16* __restrict__ Bh_, const u16* __restrict__ Bl_,
    const float* __restrict__ b1,
    u32* __restrict__ HTout,           // chunk base [4096][stride] u32-packed
    int mt0, int stride) {             // m-tile offset of chunk; chunk rows
  __shared__ __align__(16) u16 Ah[4096];
  __shared__ __align__(16) u16 Al[4096];
  __shared__ __align__(16) u16 Bh[4096];
  __shared__ __align__(16) u16 Bl[4096];
  int t = threadIdx.x;
  int wave = t >> 6, lane = t & 63;
  int nt = blockIdx.x & 31;      // 4096/128 n-tiles
  int mtl = blockIdx.x >> 5;     // m-tile local to chunk
  int wm = wave >> 1, wn = wave & 1;
  int fr = lane & 15, fg = lane >> 4;

  f32x4 acc[4][4];
#pragma unroll
  for (int i = 0; i < 4; ++i)
#pragma unroll
    for (int j = 0; j < 4; ++j) acc[i][j] = (f32x4){0.f, 0.f, 0.f, 0.f};

  const u16* pAh = Ah_ + (size_t)(mt0 + mtl) * 32 * 4096;
  const u16* pAl = Al_ + (size_t)(mt0 + mtl) * 32 * 4096;
  const u16* pBh = Bh_ + (size_t)nt * 32 * 4096;
  const u16* pBl = Bl_ + (size_t)nt * 32 * 4096;
  int so = wave * 1024 + lane * 8;   // per-lane src offset (elems), call 0
  int ld = wave * 1024;              // wave-uniform LDS dest (elems)

  for (int k0b = 0; k0b < 32; ++k0b) {
    __syncthreads();                 // previous-iter fragment reads done
    size_t sb = (size_t)k0b * 4096;
    gload16(pAh + sb + so,       &Ah[ld]);
    gload16(pAh + sb + so + 512, &Ah[ld + 512]);
    gload16(pAl + sb + so,       &Al[ld]);
    gload16(pAl + sb + so + 512, &Al[ld + 512]);
    gload16(pBh + sb + so,       &Bh[ld]);
    gload16(pBh + sb + so + 512, &Bh[ld + 512]);
    gload16(pBl + sb + so,       &Bl[ld]);
    gload16(pBl + sb + so + 512, &Bl[ld + 512]);
    __syncthreads();                 // vmcnt(0) drained by compiler before barrier
    // ---- fragments + MFMA ----
    bf16x8 ah[4], al[4], bh[4], bl[4];
#pragma unroll
    for (int i = 0; i < 4; ++i) {
      int arow = (fg * 128 + wm * 64 + i * 16 + fr) * 8;
      ah[i] = *(const bf16x8*)&Ah[arow];
      al[i] = *(const bf16x8*)&Al[arow];
      int brow = (fg * 128 + wn * 64 + i * 16 + fr) * 8;
      bh[i] = *(const bf16x8*)&Bh[brow];
      bl[i] = *(const bf16x8*)&Bl[brow];
    }
#pragma unroll
    for (int i = 0; i < 4; ++i)
#pragma unroll
      for (int j = 0; j < 4; ++j)
        acc[i][j] = __builtin_amdgcn_mfma_f32_16x16x32_bf16(ah[i], bh[j], acc[i][j], 0, 0, 0);
#pragma unroll
    for (int i = 0; i < 4; ++i)
#pragma unroll
      for (int j = 0; j < 4; ++j)
        acc[i][j] = __builtin_amdgcn_mfma_f32_16x16x32_bf16(ah[i], bl[j], acc[i][j], 0, 0, 0);
#pragma unroll
    for (int i = 0; i < 4; ++i)
#pragma unroll
      for (int j = 0; j < 4; ++j)
        acc[i][j] = __builtin_amdgcn_mfma_f32_16x16x32_bf16(al[i], bh[j], acc[i][j], 0, 0, 0);
  }

  // Epilogue (transposed, split-bf16-packed store): col=lane&15,
  // row=(lane>>4)*4+reg [m89]. r=0..3 consecutive rows -> one uint4 store.
  int colb = nt * 128 + wn * 64 + fr;
  int rowb = mtl * 128 + wm * 64 + fg * 4;
#pragma unroll
  for (int j = 0; j < 4; ++j) {
    float bias = b1[colb + j * 16];
#pragma unroll
    for (int i = 0; i < 4; ++i) {
      uint4 pk;
      u32* pp = &pk.x;
#pragma unroll
      for (int r = 0; r < 4; ++r) {
        float v = acc[i][j][r] + bias;
        v = v >= 0.0f ? v : 0.01f * v;
        unsigned short hi = f32_to_bf16(v);
        unsigned short lo = f32_to_bf16(v - bf16_to_f32(hi));
        pp[r] = ((u32)hi << 16) | lo;
      }
      *(uint4*)&HTout[(size_t)(colb + j * 16) * stride + rowb + i * 16] = pk;
    }
  }
}

// ---------------- GEMM2 (split-bf16 MFMA, streaming): Mpart = h @ W2 --------
// Numerics round-7/10/12-verified. Round-15: B-fragment DOUBLE-BUFFERING —
// the 8 W2-plane L2 loads per ks-step were issued cold and serialized
// against the MFMAs; now next-ks B frags are issued before the current MFMA
// cluster (same treatment A already has). Pure scheduling; identical values.
__global__ __launch_bounds__(64) void gemm2_bf16(
    const u32* __restrict__ hT,       // chunk base [4096][stride] u32-packed
    const u16* __restrict__ W2h,      // [64][4096] bf16 hi plane
    const u16* __restrict__ W2l,      // [64][4096] bf16 lo plane
    float* __restrict__ Mpart,        // [NPART][6400][50] fp32
    int row0, int stride) {
  int lane = threadIdx.x;
  int kz = blockIdx.y;
  int fr = lane & 15, fg = lane >> 4;

  f32x4 acc[4];
#pragma unroll
  for (int nt = 0; nt < 4; ++nt) acc[nt] = (f32x4){0.f, 0.f, 0.f, 0.f};

  const u32* hA = hT + blockIdx.x * 16 + fr;   // this lane's h-row (A row=fr)
  const int kbase = kz * 256;                  // K slice per partial
  u32 hp[8], hn[8];
#pragma unroll
  for (int kk = 0; kk < 8; ++kk)               // A frag: k = k0 + fg*8 + kk
    hp[kk] = hA[(size_t)(kbase + fg * 8 + kk) * stride];
#pragma unroll
  for (int kk = 0; kk < 8; ++kk)
    hn[kk] = hA[(size_t)(kbase + 32 + fg * 8 + kk) * stride];

  // B preload for ks=0
  bf16x8 bhc[4], blc[4];
#pragma unroll
  for (int nt = 0; nt < 4; ++nt) {
    const size_t boff = (size_t)(nt * 16 + fr) * 4096 + kbase + fg * 8;
    bhc[nt] = *(const bf16x8*)&W2h[boff];
    blc[nt] = *(const bf16x8*)&W2l[boff];
  }

  for (int ks = 0; ks < 8; ++ks) {
    int k0 = kbase + ks * 32;
    uint4 f0 = {0, 0, 0, 0}, f1 = {0, 0, 0, 0};
    (void)f0; (void)f1;
    u32 h2[8];
    if (ks < 6) {                              // A prefetch depth-2
#pragma unroll
      for (int kk = 0; kk < 8; ++kk)
        h2[kk] = hA[(size_t)(k0 + 64 + fg * 8 + kk) * stride];
    }
    bf16x8 bhn[4], bln[4];
    if (ks < 7) {                              // B prefetch depth-1
#pragma unroll
      for (int nt = 0; nt < 4; ++nt) {
        const size_t boff = (size_t)(nt * 16 + fr) * 4096 + k0 + 32 + fg * 8;
        bhn[nt] = *(const bf16x8*)&W2h[boff];
        bln[nt] = *(const bf16x8*)&W2l[boff];
      }
    }
    short8 hs, ls;
#pragma unroll
    for (int kk = 0; kk < 8; ++kk) {
      hs[kk] = (short)(hp[kk] >> 16);
      ls[kk] = (short)(hp[kk] & 0xffffu);
    }
    bf16x8 ah = *(bf16x8*)&hs;
    bf16x8 al = *(bf16x8*)&ls;
#pragma unroll
    for (int nt = 0; nt < 4; ++nt) {
      acc[nt] = __builtin_amdgcn_mfma_f32_16x16x32_bf16(ah, bhc[nt], acc[nt], 0, 0, 0);
      acc[nt] = __builtin_amdgcn_mfma_f32_16x16x32_bf16(ah, blc[nt], acc[nt], 0, 0, 0);
      acc[nt] = __builtin_amdgcn_mfma_f32_16x16x32_bf16(al, bhc[nt], acc[nt], 0, 0, 0);
    }
    if (ks < 7) {
#pragma unroll
      for (int kk = 0; kk < 8; ++kk) hp[kk] = hn[kk];
#pragma unroll
      for (int nt = 0; nt < 4; ++nt) { bhc[nt] = bhn[nt]; blc[nt] = bln[nt]; }
    }
    if (ks < 6) {
#pragma unroll
      for (int kk = 0; kk < 8; ++kk) hn[kk] = h2[kk];
    }
  }

  // D: col=lane&15, row=(lane>>4)*4+reg [m89]
  float* Mout = Mpart + (size_t)kz * PSIZE;
  int rowbase = row0 + blockIdx.x * 16 + fg * 4;
#pragma unroll
  for (int nt = 0; nt < 4; ++nt) {
    int col = nt * 16 + fr;
    if (col < NMAT) {
#pragma unroll
      for (int r = 0; r < 4; ++r)
        Mout[(size_t)(rowbase + r) * NMAT + col] = acc[nt][r];
    }
  }
}

// ---------------- Fused Sinkhorn + Hungarian (fp64, one wave per batch) -----
// Sinkhorn unchanged. Hungarian: round-12-passing structure (read-side
// register caches, deferred u-scatter) + round-14-verified f32 fast-path
// argmin. Round-15: cost array REMOVED — cost == -P algebraically, so read
// -P directly (drops the 2500-elem fill pass + 20 KB LDS; identical values).
__global__ __launch_bounds__(64) void sinkhorn_hungarian(
    const float* __restrict__ Mpart, const float* __restrict__ b2,
    float* __restrict__ out_psi, float* __restrict__ out_X,
    float* __restrict__ out_perms, float* __restrict__ out_dist) {
  int b = blockIdx.x, lane = threadIdx.x;
  __shared__ double P[2500];
  __shared__ double rs[50];
  __shared__ double u[51];
  __shared__ int p[51];
  __shared__ int wayl[51];
  const size_t base = (size_t)b * 2500;

  // ---- Sinkhorn ----
  for (int e = lane; e < 2500; e += 64) {
    double m = 0.0;
#pragma unroll
    for (int pz = 0; pz < NPART; ++pz)
      m += (double)Mpart[(size_t)pz * PSIZE + base + e];
    m += (double)b2[e % 50];
    m = m >= 0.0 ? m : 0.01 * m;      // leaky_relu in fp64
    P[e] = exp(m);                    // TAU = 1.0
  }
  __syncthreads();
  for (int it = 0; it < 5; ++it) {
    if (lane < 50) { double s = 0; for (int j = 0; j < 50; ++j) s += P[lane * 50 + j]; rs[lane] = s; }
    __syncthreads();
    for (int e = lane; e < 2500; e += 64) P[e] /= rs[e / 50];   // axis=2
    __syncthreads();
    if (lane < 50) { double s = 0; for (int r = 0; r < 50; ++r) s += P[r * 50 + lane]; rs[lane] = s; }
    __syncthreads();
    for (int e = lane; e < 2500; e += 64) P[e] /= rs[e % 50];   // axis=1
    __syncthreads();
  }
  for (int e = lane; e < 2500; e += 64) {
    float f = (float)P[e];
    out_psi[base + e] = f;
    out_X[base + e] = f;              // ALPHA=1.0 => X == psi exactly
  }
  if (lane < 51) { u[lane] = 0.0; p[lane] = 0; }
  __syncthreads();

  // ---- Hungarian ----
  double v = 0.0;                      // v[lane+1], lane-local (round-7 proven)
  bool lactive = lane < NMAT;
  for (int i = 1; i <= NMAT; ++i) {
    // uniform register caches (all lanes execute these reads; no divergence)
    int pc = (lane <= 50) ? p[lane] : 0;           // p[j] on lane j
    double uc = (lane < 50) ? u[lane + 1] : 0.0;   // u[row] on lane row-1
    bool used = false;
    int way = 0;
    int j0 = 0, j1 = 0;
    double uacc = 0.0, total = 0.0;
    for (int guard = 0; guard < 64; ++guard) {   // defensive cap (normally <=51)
      if (lane == j0 - 1) used = true;           // used[j0] = True (j0>=1)
      int j0u = __builtin_amdgcn_readfirstlane(j0);
      int i0 = (j0u == 0) ? i : __builtin_amdgcn_readlane(pc, j0u);
      double ui0 = readlane_f64(uc, i0 - 1);     // loop-start u (invariant)
      double cand = HINF;
      if (lactive && !used) {
        cand = -P[(i0 - 1) * NMAT + lane] - ui0 - v;   // cost == -P
        way = j0;                                // dead-minv replica
      }
      // f32 fast-path argmin (monotone conversion; exact f64 fixup)
      float cf = (float)cand;
      float mf = wave_min_f32(cf);
      unsigned long long balf = __ballot(cf == mf);
      double m;
      if (__builtin_popcountll(balf) == 1) {     // unique f32 min -> exact
        int lmin = (int)__builtin_ctzll(balf);
        m = readlane_f64(cand, lmin);
        j1 = lmin + 1;
      } else {                                   // rare f32 tie: exact f64 path
        double candt = (cf == mf) ? cand : HINF;
        m = wave_min_f64(candt);
        unsigned long long bal = __ballot(cand == m);
        j1 = (int)__builtin_ctzll(bal) + 1;      // lowest-j among true f64 min
      }
      if (used) { v -= m; uacc += m; }           // v[used]-=d; defer u[p[used]]+=d
      total += m;                                // row i accumulates ALL deltas
      j0 = j1;
      int j1u = __builtin_amdgcn_readfirstlane(j0);
      if (__builtin_amdgcn_readlane(pc, j1u) == 0) break;   // p static in-loop
    }
    // deferred u-scatter: same targets/values as round-7's per-step updates
    if (used && lactive) u[p[lane + 1]] += uacc; // distinct rows (p injective)
    if (lane == 63) u[i] += total;               // virtual col 0: p[0]=i
    if (lactive) wayl[lane + 1] = way;
    __syncthreads();
    if (lane == 0) {                   // augment (serial; path <= 50, bounded)
      int j = j1;
      for (int step = 0; step < 64 && j != 0; ++step) {
        int jw = wayl[j];
        p[j] = (jw == 0) ? i : p[jw];
        j = jw;
      }
    }
    __syncthreads();
  }

  // perms one-hot + dist (fp32 outputs)
  size_t pbase = (size_t)b * 2500;
  for (int e = lane; e < 2500; e += 64) out_perms[pbase + e] = 0.0f;
  __syncthreads();
  double val = 0.0;
  if (lactive) {
    int row = p[lane + 1] - 1;
    if (row < 0) row = 0;              // defensive clamp (provably unreachable)
    if (row > 49) row = 49;
    out_perms[pbase + (size_t)row * NMAT + lane] = 1.0f;
    val = P[(size_t)row * NMAT + lane];
  }
#pragma unroll
  for (int s = 32; s > 0; s >>= 1) val += __shfl_xor(val, s, 64);
  if (lane == 0) out_dist[b] = (float)(val / (double)NMAT);
}

// ---------------------------------------------------------------------------
extern "C" void kernel_launch(void* const* d_in, const int* in_sizes, int n_in,
                              void* d_out, int out_size, void* d_ws, size_t ws_size,
                              hipStream_t stream) {
  const float* x  = (const float*)d_in[0];   // fp32 per the reference dtypes
  const float* W1 = (const float*)d_in[1];
  const float* b1 = (const float*)d_in[2];
  const float* W2 = (const float*)d_in[3];
  const float* b2 = (const float*)d_in[4];
  float* out = (float*)d_out;                // outputs float32 (round-8/11 finding)
  float* out_psi   = out;
  float* out_perms = out + PSIZE;
  float* out_X     = out + 2 * PSIZE;
  float* out_dist  = out + 3 * PSIZE;

  if (ws_size < (size_t)WS_MIN) return;

  char* ws = (char*)d_ws;
  float* Mpart = (float*)(ws + WS_M_OFF);
  u16* Xh  = (u16*)(ws + WS_XH_OFF);
  u16* Xl  = (u16*)(ws + WS_XL_OFF);
  u16* W1h = (u16*)(ws + WS_W1H_OFF);
  u16* W1l = (u16*)(ws + WS_W1L_OFF);
  u16* W2h = (u16*)(ws + WS_W2H_OFF);
  u16* W2l = (u16*)(ws + WS_W2L_OFF);
  u32* hbuf = (u32*)(ws + WS_H_OFF);
  long long avail = (long long)ws_size - WS_H_OFF;
  int max_rows = (int)(avail / (HDIM * 4));
  max_rows = (max_rows / 128) * 128;
  if (max_rows > ROWS) max_rows = ROWS;

  // one-time conversions: split-bf16 pack (X, W1) + split-bf16 W2^T planes
  hipLaunchKernelGGL(convert_x, dim3(1600), dim3(256), 0, stream, x, Xh, Xl);
  hipLaunchKernelGGL(convert_w1, dim3(1024), dim3(256), 0, stream, W1, W1h, W1l);
  hipLaunchKernelGGL(convert_w2, dim3(1024), dim3(256), 0, stream, W2, W2h, W2l);

  for (int r0 = 0; r0 < ROWS; r0 += max_rows) {
    int rows = (ROWS - r0 < max_rows) ? (ROWS - r0) : max_rows;
    hipLaunchKernelGGL(gemm1_mfma, dim3((rows / 128) * 32), dim3(256), 0, stream,
                       Xh, Xl, W1h, W1l, b1, hbuf, r0 / 128, rows);
    hipLaunchKernelGGL(gemm2_bf16, dim3(rows / 16, NPART), dim3(64), 0, stream,
                       hbuf, W2h, W2l, Mpart, r0, rows);
  }
  hipLaunchKernelGGL(sinkhorn_hungarian, dim3(BATCH), dim3(64), 0, stream,
                     Mpart, b2, out_psi, out_X, out_perms, out_dist);
}

// Round 16
// 467.069 us; speedup vs baseline: 1.0192x; 1.0192x over previous
//
#include <hip/hip_runtime.h>

// Problem constants
#define NMAT 50
#define BATCH 128
#define FDIM 1024
#define HDIM 4096
#define ROWS 6400            // BATCH*NMAT
#define PSIZE 320000         // BATCH*NMAT*NMAT
#define NPART 32             // split-K partials for gemm2
#define HINF 1e18

// ws layout (bytes):
//   Mpart : fp32 [32][6400][50] split-K partials (40.96 MB)
//   Xh/Xl : packed split-bf16 X     [50 mt][32 k0b][4 kg][128 m][8] 13.1 MB each
//   W1h/l : packed split-bf16 W1^T  [32 nt][32 k0b][4 kg][128 n][8] 8.39 MB each
//   W2h/l : bf16 W2^T planes [64][4096] (cols>=50 zero), 512 KB each, L2-resident
//   hbuf  : u32 hT-packed [4096][max_rows]: (bf16hi<<16)|bf16lo of h^T
#define WS_M_OFF   0
#define WS_XH_OFF  40960000LL
#define WS_XL_OFF  54067200LL
#define WS_W1H_OFF 67174400LL
#define WS_W1L_OFF 75563008LL
#define WS_W2H_OFF 83951616LL
#define WS_W2L_OFF 84475904LL
#define WS_H_OFF   85000192LL
#define WS_MIN     (WS_H_OFF + 128LL * HDIM * 4)   // ~87.1 MB

typedef __bf16 bf16x8 __attribute__((ext_vector_type(8)));
typedef short short8 __attribute__((ext_vector_type(8)));
typedef float f32x4 __attribute__((ext_vector_type(4)));
typedef unsigned short u16;
typedef unsigned int u32;

__device__ __forceinline__ float bf16_to_f32(unsigned short h) {
  return __uint_as_float(((unsigned int)h) << 16);
}
__device__ __forceinline__ unsigned short f32_to_bf16(float f) {
  unsigned int u = __float_as_uint(f);
  u += 0x7FFFu + ((u >> 16) & 1u);   // RNE
  return (unsigned short)(u >> 16);
}

// async global->LDS, 16B per lane; LDS dest = wave-uniform base + lane*16
__device__ __forceinline__ void gload16(const u16* g, u16* l) {
  __builtin_amdgcn_global_load_lds(
      (const __attribute__((address_space(1))) unsigned int*)g,
      (__attribute__((address_space(3))) unsigned int*)l, 16, 0, 0);
}

// ---- wave-wide fp64 min via DPP (round-5..15 verified) ----
__device__ __forceinline__ double wave_min_f64(double x) {
  union { double d; int i[2]; } u, t;
  u.d = x;
#define DPP_MIN_STEP(ctrl)                                                   \
  t.i[0] = __builtin_amdgcn_update_dpp(u.i[0], u.i[0], ctrl, 0xf, 0xf, false);\
  t.i[1] = __builtin_amdgcn_update_dpp(u.i[1], u.i[1], ctrl, 0xf, 0xf, false);\
  u.d = fmin(u.d, t.d);
  DPP_MIN_STEP(0x111)  // row_shr:1
  DPP_MIN_STEP(0x112)  // row_shr:2
  DPP_MIN_STEP(0x114)  // row_shr:4
  DPP_MIN_STEP(0x118)  // row_shr:8
  DPP_MIN_STEP(0x142)  // row_bcast15
  DPP_MIN_STEP(0x143)  // row_bcast31
#undef DPP_MIN_STEP
  union { double d; int i[2]; } r;
  r.i[0] = __builtin_amdgcn_readlane(u.i[0], 63);
  r.i[1] = __builtin_amdgcn_readlane(u.i[1], 63);
  return r.d;
}

// ---- wave-wide fp32 min via DPP (round-14/15 verified) ----
__device__ __forceinline__ float wave_min_f32(float x) {
  float t;
#define DPP_MINF_STEP(ctrl)                                                  \
  t = __uint_as_float(__builtin_amdgcn_update_dpp(                           \
      (int)__float_as_uint(x), (int)__float_as_uint(x), ctrl, 0xf, 0xf, false));\
  x = fminf(x, t);
  DPP_MINF_STEP(0x111)
  DPP_MINF_STEP(0x112)
  DPP_MINF_STEP(0x114)
  DPP_MINF_STEP(0x118)
  DPP_MINF_STEP(0x142)
  DPP_MINF_STEP(0x143)
#undef DPP_MINF_STEP
  return __uint_as_float(__builtin_amdgcn_readlane((int)__float_as_uint(x), 63));
}

// ---- f64 broadcast-read of one lane's value (uniform index) ----
__device__ __forceinline__ double readlane_f64(double x, int l) {
  union { double d; int i2[2]; } a, b;
  a.d = x;
  b.i2[0] = __builtin_amdgcn_readlane(a.i2[0], l);
  b.i2[1] = __builtin_amdgcn_readlane(a.i2[1], l);
  return b.d;
}

// ---------------- fused pre-pass: split-bf16 pack of X, W1^T, W2^T ----------
// One launch (saves 2 stream-serialized launch gaps). Block ranges:
//   [0,1600)      X  : out [mt][k0b][kg][128 m][8], bx = mt*32 + k0b
//   [1600,2624)   W1 : out [nt][k0b][kg][128 n][8], transposed gather
//   [2624,3648)   W2 : out hi/lo planes [64 n][4096 k], cols >= 50 zero
__global__ __launch_bounds__(256) void convert_all(
    const float* __restrict__ X, u16* __restrict__ Xh, u16* __restrict__ Xl,
    const float* __restrict__ W1, u16* __restrict__ W1h, u16* __restrict__ W1l,
    const float* __restrict__ W2, u16* __restrict__ W2h, u16* __restrict__ W2l) {
  int b = blockIdx.x, t = threadIdx.x;
  if (b < 1600) {
    int mt = b >> 5, k0b = b & 31;
    size_t outbase = (size_t)b * 4096;
#pragma unroll
    for (int it = 0; it < 2; ++it) {
      int idx = t + it * 256;
      int m = idx & 127, kg = idx >> 7;
      const float* src = X + (size_t)(mt * 128 + m) * FDIM + k0b * 32 + kg * 8;
      float4 v0 = *(const float4*)src;
      float4 v1 = *(const float4*)(src + 4);
      float f[8] = {v0.x, v0.y, v0.z, v0.w, v1.x, v1.y, v1.z, v1.w};
      unsigned short h[8], l[8];
#pragma unroll
      for (int j = 0; j < 8; ++j) {
        h[j] = f32_to_bf16(f[j]);
        l[j] = f32_to_bf16(f[j] - bf16_to_f32(h[j]));
      }
      uint4 hv, lv;
      hv.x = h[0] | ((unsigned)h[1] << 16); hv.y = h[2] | ((unsigned)h[3] << 16);
      hv.z = h[4] | ((unsigned)h[5] << 16); hv.w = h[6] | ((unsigned)h[7] << 16);
      lv.x = l[0] | ((unsigned)l[1] << 16); lv.y = l[2] | ((unsigned)l[3] << 16);
      lv.z = l[4] | ((unsigned)l[5] << 16); lv.w = l[6] | ((unsigned)l[7] << 16);
      size_t off = outbase + (size_t)(kg * 128 + m) * 8;
      *(uint4*)&Xh[off] = hv;
      *(uint4*)&Xl[off] = lv;
    }
  } else if (b < 2624) {
    int bx = b - 1600;
    int nt = bx >> 5, k0b = bx & 31;
    size_t outbase = (size_t)bx * 4096;
#pragma unroll
    for (int it = 0; it < 2; ++it) {
      int idx = t + it * 256;
      int n = idx & 127, kg = idx >> 7;
      float f[8];
#pragma unroll
      for (int j = 0; j < 8; ++j)
        f[j] = W1[(size_t)(k0b * 32 + kg * 8 + j) * HDIM + nt * 128 + n];
      unsigned short h[8], l[8];
#pragma unroll
      for (int j = 0; j < 8; ++j) {
        h[j] = f32_to_bf16(f[j]);
        l[j] = f32_to_bf16(f[j] - bf16_to_f32(h[j]));
      }
      uint4 hv, lv;
      hv.x = h[0] | ((unsigned)h[1] << 16); hv.y = h[2] | ((unsigned)h[3] << 16);
      hv.z = h[4] | ((unsigned)h[5] << 16); hv.w = h[6] | ((unsigned)h[7] << 16);
      lv.x = l[0] | ((unsigned)l[1] << 16); lv.y = l[2] | ((unsigned)l[3] << 16);
      lv.z = l[4] | ((unsigned)l[5] << 16); lv.w = l[6] | ((unsigned)l[7] << 16);
      size_t off = outbase + (size_t)(kg * 128 + n) * 8;
      *(uint4*)&W1h[off] = hv;
      *(uint4*)&W1l[off] = lv;
    }
  } else {
    int idx = (b - 2624) * 256 + t;           // 64*4096 elems
    int n = idx >> 12, k = idx & 4095;
    float f = (n < NMAT) ? W2[(size_t)k * NMAT + n] : 0.0f;
    unsigned short hi = f32_to_bf16(f);
    unsigned short lo = f32_to_bf16(f - bf16_to_f32(hi));
    W2h[idx] = hi;
    W2l[idx] = lo;
  }
}

// ---------------- GEMM1 (split-bf16 MFMA): h = leaky(x @ W1 + b1) -----------
// 128x128 tile, BK=32, 4 waves, 48 MFMA per k-step; staging via
// global_load_lds width-16 only. Epilogue: TRANSPOSED uint4 stores
// (hT[col][row]) — round-12/15-verified (row-major scalar stores cost +15 us
// and +20% WRITE_SIZE; reverted in round 15).
__global__ __launch_bounds__(256) void gemm1_mfma(
    const u16* __restrict__ Ah_, const u16* __restrict__ Al_,
    const u16* __restrict__ Bh_, const u16* __restrict__ Bl_,
    const float* __restrict__ b1,
    u32* __restrict__ HTout,           // chunk base [4096][stride] u32-packed
    int mt0, int stride) {             // m-tile offset of chunk; chunk rows
  __shared__ __align__(16) u16 Ah[4096];
  __shared__ __align__(16) u16 Al[4096];
  __shared__ __align__(16) u16 Bh[4096];
  __shared__ __align__(16) u16 Bl[4096];
  int t = threadIdx.x;
  int wave = t >> 6, lane = t & 63;
  int nt = blockIdx.x & 31;      // 4096/128 n-tiles
  int mtl = blockIdx.x >> 5;     // m-tile local to chunk
  int wm = wave >> 1, wn = wave & 1;
  int fr = lane & 15, fg = lane >> 4;

  f32x4 acc[4][4];
#pragma unroll
  for (int i = 0; i < 4; ++i)
#pragma unroll
    for (int j = 0; j < 4; ++j) acc[i][j] = (f32x4){0.f, 0.f, 0.f, 0.f};

  const u16* pAh = Ah_ + (size_t)(mt0 + mtl) * 32 * 4096;
  const u16* pAl = Al_ + (size_t)(mt0 + mtl) * 32 * 4096;
  const u16* pBh = Bh_ + (size_t)nt * 32 * 4096;
  const u16* pBl = Bl_ + (size_t)nt * 32 * 4096;
  int so = wave * 1024 + lane * 8;   // per-lane src offset (elems), call 0
  int ld = wave * 1024;              // wave-uniform LDS dest (elems)

  for (int k0b = 0; k0b < 32; ++k0b) {
    __syncthreads();                 // previous-iter fragment reads done
    size_t sb = (size_t)k0b * 4096;
    gload16(pAh + sb + so,       &Ah[ld]);
    gload16(pAh + sb + so + 512, &Ah[ld + 512]);
    gload16(pAl + sb + so,       &Al[ld]);
    gload16(pAl + sb + so + 512, &Al[ld + 512]);
    gload16(pBh + sb + so,       &Bh[ld]);
    gload16(pBh + sb + so + 512, &Bh[ld + 512]);
    gload16(pBl + sb + so,       &Bl[ld]);
    gload16(pBl + sb + so + 512, &Bl[ld + 512]);
    __syncthreads();                 // vmcnt(0) drained by compiler before barrier
    // ---- fragments + MFMA ----
    bf16x8 ah[4], al[4], bh[4], bl[4];
#pragma unroll
    for (int i = 0; i < 4; ++i) {
      int arow = (fg * 128 + wm * 64 + i * 16 + fr) * 8;
      ah[i] = *(const bf16x8*)&Ah[arow];
      al[i] = *(const bf16x8*)&Al[arow];
      int brow = (fg * 128 + wn * 64 + i * 16 + fr) * 8;
      bh[i] = *(const bf16x8*)&Bh[brow];
      bl[i] = *(const bf16x8*)&Bl[brow];
    }
#pragma unroll
    for (int i = 0; i < 4; ++i)
#pragma unroll
      for (int j = 0; j < 4; ++j)
        acc[i][j] = __builtin_amdgcn_mfma_f32_16x16x32_bf16(ah[i], bh[j], acc[i][j], 0, 0, 0);
#pragma unroll
    for (int i = 0; i < 4; ++i)
#pragma unroll
      for (int j = 0; j < 4; ++j)
        acc[i][j] = __builtin_amdgcn_mfma_f32_16x16x32_bf16(ah[i], bl[j], acc[i][j], 0, 0, 0);
#pragma unroll
    for (int i = 0; i < 4; ++i)
#pragma unroll
      for (int j = 0; j < 4; ++j)
        acc[i][j] = __builtin_amdgcn_mfma_f32_16x16x32_bf16(al[i], bh[j], acc[i][j], 0, 0, 0);
  }

  // Epilogue (transposed, split-bf16-packed store): col=lane&15,
  // row=(lane>>4)*4+reg [m89]. r=0..3 consecutive rows -> one uint4 store.
  int colb = nt * 128 + wn * 64 + fr;
  int rowb = mtl * 128 + wm * 64 + fg * 4;
#pragma unroll
  for (int j = 0; j < 4; ++j) {
    float bias = b1[colb + j * 16];
#pragma unroll
    for (int i = 0; i < 4; ++i) {
      uint4 pk;
      u32* pp = &pk.x;
#pragma unroll
      for (int r = 0; r < 4; ++r) {
        float v = acc[i][j][r] + bias;
        v = v >= 0.0f ? v : 0.01f * v;
        unsigned short hi = f32_to_bf16(v);
        unsigned short lo = f32_to_bf16(v - bf16_to_f32(hi));
        pp[r] = ((u32)hi << 16) | lo;
      }
      *(uint4*)&HTout[(size_t)(colb + j * 16) * stride + rowb + i * 16] = pk;
    }
  }
}

// ---------------- GEMM2 (split-bf16 MFMA, streaming): Mpart = h @ W2 --------
// Numerics round-7/10/12-verified body. Round-16: NPART 16->32 (K-slice 128,
// 4 ks-steps; 12800 waves ~12.5/SIMD) — the only lever gemm2 has responded
// to (TLP: -17, -15 at 4->8->16). B-dbuf dropped (round-15 null: compiler
// already hoists B loads). A depth-2 prefetch retained.
__global__ __launch_bounds__(64) void gemm2_bf16(
    const u32* __restrict__ hT,       // chunk base [4096][stride] u32-packed
    const u16* __restrict__ W2h,      // [64][4096] bf16 hi plane
    const u16* __restrict__ W2l,      // [64][4096] bf16 lo plane
    float* __restrict__ Mpart,        // [NPART][6400][50] fp32
    int row0, int stride) {
  int lane = threadIdx.x;
  int kz = blockIdx.y;
  int fr = lane & 15, fg = lane >> 4;

  f32x4 acc[4];
#pragma unroll
  for (int nt = 0; nt < 4; ++nt) acc[nt] = (f32x4){0.f, 0.f, 0.f, 0.f};

  const u32* hA = hT + blockIdx.x * 16 + fr;   // this lane's h-row (A row=fr)
  const int kbase = kz * 128;                  // K slice per partial
  u32 hp[8], hn[8];
#pragma unroll
  for (int kk = 0; kk < 8; ++kk)               // A frag: k = k0 + fg*8 + kk
    hp[kk] = hA[(size_t)(kbase + fg * 8 + kk) * stride];
#pragma unroll
  for (int kk = 0; kk < 8; ++kk)
    hn[kk] = hA[(size_t)(kbase + 32 + fg * 8 + kk) * stride];

  for (int ks = 0; ks < 4; ++ks) {
    int k0 = kbase + ks * 32;
    u32 h2[8];
    if (ks < 2) {                              // A prefetch depth-2
#pragma unroll
      for (int kk = 0; kk < 8; ++kk)
        h2[kk] = hA[(size_t)(k0 + 64 + fg * 8 + kk) * stride];
    }
    short8 hs, ls;
#pragma unroll
    for (int kk = 0; kk < 8; ++kk) {
      hs[kk] = (short)(hp[kk] >> 16);
      ls[kk] = (short)(hp[kk] & 0xffffu);
    }
    bf16x8 ah = *(bf16x8*)&hs;
    bf16x8 al = *(bf16x8*)&ls;
#pragma unroll
    for (int nt = 0; nt < 4; ++nt) {           // B frag: col=fr, k=k0+fg*8..
      const size_t boff = (size_t)(nt * 16 + fr) * 4096 + k0 + fg * 8;
      bf16x8 bh = *(const bf16x8*)&W2h[boff];
      bf16x8 bl = *(const bf16x8*)&W2l[boff];
      acc[nt] = __builtin_amdgcn_mfma_f32_16x16x32_bf16(ah, bh, acc[nt], 0, 0, 0);
      acc[nt] = __builtin_amdgcn_mfma_f32_16x16x32_bf16(ah, bl, acc[nt], 0, 0, 0);
      acc[nt] = __builtin_amdgcn_mfma_f32_16x16x32_bf16(al, bh, acc[nt], 0, 0, 0);
    }
    if (ks < 3) {
#pragma unroll
      for (int kk = 0; kk < 8; ++kk) hp[kk] = hn[kk];
    }
    if (ks < 2) {
#pragma unroll
      for (int kk = 0; kk < 8; ++kk) hn[kk] = h2[kk];
    }
  }

  // D: col=lane&15, row=(lane>>4)*4+reg [m89]
  float* Mout = Mpart + (size_t)kz * PSIZE;
  int rowbase = row0 + blockIdx.x * 16 + fg * 4;
#pragma unroll
  for (int nt = 0; nt < 4; ++nt) {
    int col = nt * 16 + fr;
    if (col < NMAT) {
#pragma unroll
      for (int r = 0; r < 4; ++r)
        Mout[(size_t)(rowbase + r) * NMAT + col] = acc[nt][r];
    }
  }
}

// ---------------- Fused Sinkhorn + Hungarian (fp64, one wave per batch) -----
// Round-15-verified body (register caches, deferred u-scatter, f32 fast-path
// argmin with exact f64 fixup, cost == -P direct read). NPART merge -> 32.
__global__ __launch_bounds__(64) void sinkhorn_hungarian(
    const float* __restrict__ Mpart, const float* __restrict__ b2,
    float* __restrict__ out_psi, float* __restrict__ out_X,
    float* __restrict__ out_perms, float* __restrict__ out_dist) {
  int b = blockIdx.x, lane = threadIdx.x;
  __shared__ double P[2500];
  __shared__ double rs[50];
  __shared__ double u[51];
  __shared__ int p[51];
  __shared__ int wayl[51];
  const size_t base = (size_t)b * 2500;

  // ---- Sinkhorn ----
  for (int e = lane; e < 2500; e += 64) {
    double m = 0.0;
#pragma unroll
    for (int pz = 0; pz < NPART; ++pz)
      m += (double)Mpart[(size_t)pz * PSIZE + base + e];
    m += (double)b2[e % 50];
    m = m >= 0.0 ? m : 0.01 * m;      // leaky_relu in fp64
    P[e] = exp(m);                    // TAU = 1.0
  }
  __syncthreads();
  for (int it = 0; it < 5; ++it) {
    if (lane < 50) { double s = 0; for (int j = 0; j < 50; ++j) s += P[lane * 50 + j]; rs[lane] = s; }
    __syncthreads();
    for (int e = lane; e < 2500; e += 64) P[e] /= rs[e / 50];   // axis=2
    __syncthreads();
    if (lane < 50) { double s = 0; for (int r = 0; r < 50; ++r) s += P[r * 50 + lane]; rs[lane] = s; }
    __syncthreads();
    for (int e = lane; e < 2500; e += 64) P[e] /= rs[e % 50];   // axis=1
    __syncthreads();
  }
  for (int e = lane; e < 2500; e += 64) {
    float f = (float)P[e];
    out_psi[base + e] = f;
    out_X[base + e] = f;              // ALPHA=1.0 => X == psi exactly
  }
  if (lane < 51) { u[lane] = 0.0; p[lane] = 0; }
  __syncthreads();

  // ---- Hungarian ----
  double v = 0.0;                      // v[lane+1], lane-local (round-7 proven)
  bool lactive = lane < NMAT;
  for (int i = 1; i <= NMAT; ++i) {
    // uniform register caches (all lanes execute these reads; no divergence)
    int pc = (lane <= 50) ? p[lane] : 0;           // p[j] on lane j
    double uc = (lane < 50) ? u[lane + 1] : 0.0;   // u[row] on lane row-1
    bool used = false;
    int way = 0;
    int j0 = 0, j1 = 0;
    double uacc = 0.0, total = 0.0;
    for (int guard = 0; guard < 64; ++guard) {   // defensive cap (normally <=51)
      if (lane == j0 - 1) used = true;           // used[j0] = True (j0>=1)
      int j0u = __builtin_amdgcn_readfirstlane(j0);
      int i0 = (j0u == 0) ? i : __builtin_amdgcn_readlane(pc, j0u);
      double ui0 = readlane_f64(uc, i0 - 1);     // loop-start u (invariant)
      double cand = HINF;
      if (lactive && !used) {
        cand = -P[(i0 - 1) * NMAT + lane] - ui0 - v;   // cost == -P
        way = j0;                                // dead-minv replica
      }
      // f32 fast-path argmin (monotone conversion; exact f64 fixup)
      float cf = (float)cand;
      float mf = wave_min_f32(cf);
      unsigned long long balf = __ballot(cf == mf);
      double m;
      if (__builtin_popcountll(balf) == 1) {     // unique f32 min -> exact
        int lmin = (int)__builtin_ctzll(balf);
        m = readlane_f64(cand, lmin);
        j1 = lmin + 1;
      } else {                                   // rare f32 tie: exact f64 path
        double candt = (cf == mf) ? cand : HINF;
        m = wave_min_f64(candt);
        unsigned long long bal = __ballot(cand == m);
        j1 = (int)__builtin_ctzll(bal) + 1;      // lowest-j among true f64 min
      }
      if (used) { v -= m; uacc += m; }           // v[used]-=d; defer u[p[used]]+=d
      total += m;                                // row i accumulates ALL deltas
      j0 = j1;
      int j1u = __builtin_amdgcn_readfirstlane(j0);
      if (__builtin_amdgcn_readlane(pc, j1u) == 0) break;   // p static in-loop
    }
    // deferred u-scatter: same targets/values as round-7's per-step updates
    if (used && lactive) u[p[lane + 1]] += uacc; // distinct rows (p injective)
    if (lane == 63) u[i] += total;               // virtual col 0: p[0]=i
    if (lactive) wayl[lane + 1] = way;
    __syncthreads();
    if (lane == 0) {                   // augment (serial; path <= 50, bounded)
      int j = j1;
      for (int step = 0; step < 64 && j != 0; ++step) {
        int jw = wayl[j];
        p[j] = (jw == 0) ? i : p[jw];
        j = jw;
      }
    }
    __syncthreads();
  }

  // perms one-hot + dist (fp32 outputs)
  size_t pbase = (size_t)b * 2500;
  for (int e = lane; e < 2500; e += 64) out_perms[pbase + e] = 0.0f;
  __syncthreads();
  double val = 0.0;
  if (lactive) {
    int row = p[lane + 1] - 1;
    if (row < 0) row = 0;              // defensive clamp (provably unreachable)
    if (row > 49) row = 49;
    out_perms[pbase + (size_t)row * NMAT + lane] = 1.0f;
    val = P[(size_t)row * NMAT + lane];
  }
#pragma unroll
  for (int s = 32; s > 0; s >>= 1) val += __shfl_xor(val, s, 64);
  if (lane == 0) out_dist[b] = (float)(val / (double)NMAT);
}

// ---------------------------------------------------------------------------
extern "C" void kernel_launch(void* const* d_in, const int* in_sizes, int n_in,
                              void* d_out, int out_size, void* d_ws, size_t ws_size,
                              hipStream_t stream) {
  const float* x  = (const float*)d_in[0];   // fp32 per the reference dtypes
  const float* W1 = (const float*)d_in[1];
  const float* b1 = (const float*)d_in[2];
  const float* W2 = (const float*)d_in[3];
  const float* b2 = (const float*)d_in[4];
  float* out = (float*)d_out;                // outputs float32 (round-8/11 finding)
  float* out_psi   = out;
  float* out_perms = out + PSIZE;
  float* out_X     = out + 2 * PSIZE;
  float* out_dist  = out + 3 * PSIZE;

  if (ws_size < (size_t)WS_MIN) return;

  char* ws = (char*)d_ws;
  float* Mpart = (float*)(ws + WS_M_OFF);
  u16* Xh  = (u16*)(ws + WS_XH_OFF);
  u16* Xl  = (u16*)(ws + WS_XL_OFF);
  u16* W1h = (u16*)(ws + WS_W1H_OFF);
  u16* W1l = (u16*)(ws + WS_W1L_OFF);
  u16* W2h = (u16*)(ws + WS_W2H_OFF);
  u16* W2l = (u16*)(ws + WS_W2L_OFF);
  u32* hbuf = (u32*)(ws + WS_H_OFF);
  long long avail = (long long)ws_size - WS_H_OFF;
  int max_rows = (int)(avail / (HDIM * 4));
  max_rows = (max_rows / 128) * 128;
  if (max_rows > ROWS) max_rows = ROWS;

  // one-time split-bf16 conversion + packing (fused single launch)
  hipLaunchKernelGGL(convert_all, dim3(3648), dim3(256), 0, stream,
                     x, Xh, Xl, W1, W1h, W1l, W2, W2h, W2l);

  for (int r0 = 0; r0 < ROWS; r0 += max_rows) {
    int rows = (ROWS - r0 < max_rows) ? (ROWS - r0) : max_rows;
    hipLaunchKernelGGL(gemm1_mfma, dim3((rows / 128) * 32), dim3(256), 0, stream,
                       Xh, Xl, W1h, W1l, b1, hbuf, r0 / 128, rows);
    hipLaunchKernelGGL(gemm2_bf16, dim3(rows / 16, NPART), dim3(64), 0, stream,
                       hbuf, W2h, W2l, Mpart, r0, rows);
  }
  hipLaunchKernelGGL(sinkhorn_hungarian, dim3(BATCH), dim3(64), 0, stream,
                     Mpart, b2, out_psi, out_X, out_perms, out_dist);
}

// Round 17
// 457.231 us; speedup vs baseline: 1.0411x; 1.0215x over previous
//
#include <hip/hip_runtime.h>

// Problem constants
#define NMAT 50
#define BATCH 128
#define FDIM 1024
#define HDIM 4096
#define ROWS 6400            // BATCH*NMAT
#define PSIZE 320000         // BATCH*NMAT*NMAT
#define NPART 32             // split-K partials for gemm2
#define HINF 1e18

// ws layout (bytes):
//   Mpart : fp32 [32][6400][50] split-K partials (40.96 MB)
//   Xh/Xl : packed split-bf16 X     [50 mt][32 k0b][4 kg][128 m][8] 13.1 MB each
//   W1h/l : packed split-bf16 W1^T  [32 nt][32 k0b][4 kg][128 n][8] 8.39 MB each
//   W2h/l : bf16 W2^T planes [64][4096] (cols>=50 zero), 512 KB each, L2-resident
//   hbuf  : u32 hT-packed [4096][max_rows]; after gemm2 finishes the region is
//           dead and REUSED for Mmerged fp64 [6400][50] (2.56 MB)
#define WS_M_OFF   0
#define WS_XH_OFF  40960000LL
#define WS_XL_OFF  54067200LL
#define WS_W1H_OFF 67174400LL
#define WS_W1L_OFF 75563008LL
#define WS_W2H_OFF 83951616LL
#define WS_W2L_OFF 84475904LL
#define WS_H_OFF   85000192LL
#define WS_MIN     (WS_H_OFF + 128LL * HDIM * 4)   // ~87.1 MB

typedef __bf16 bf16x8 __attribute__((ext_vector_type(8)));
typedef short short8 __attribute__((ext_vector_type(8)));
typedef float f32x4 __attribute__((ext_vector_type(4)));
typedef unsigned short u16;
typedef unsigned int u32;

__device__ __forceinline__ float bf16_to_f32(unsigned short h) {
  return __uint_as_float(((unsigned int)h) << 16);
}
__device__ __forceinline__ unsigned short f32_to_bf16(float f) {
  unsigned int u = __float_as_uint(f);
  u += 0x7FFFu + ((u >> 16) & 1u);   // RNE
  return (unsigned short)(u >> 16);
}

// async global->LDS, 16B per lane; LDS dest = wave-uniform base + lane*16
__device__ __forceinline__ void gload16(const u16* g, u16* l) {
  __builtin_amdgcn_global_load_lds(
      (const __attribute__((address_space(1))) unsigned int*)g,
      (__attribute__((address_space(3))) unsigned int*)l, 16, 0, 0);
}

// ---- wave-wide fp64 min via DPP (round-5..16 verified) ----
__device__ __forceinline__ double wave_min_f64(double x) {
  union { double d; int i[2]; } u, t;
  u.d = x;
#define DPP_MIN_STEP(ctrl)                                                   \
  t.i[0] = __builtin_amdgcn_update_dpp(u.i[0], u.i[0], ctrl, 0xf, 0xf, false);\
  t.i[1] = __builtin_amdgcn_update_dpp(u.i[1], u.i[1], ctrl, 0xf, 0xf, false);\
  u.d = fmin(u.d, t.d);
  DPP_MIN_STEP(0x111)  // row_shr:1
  DPP_MIN_STEP(0x112)  // row_shr:2
  DPP_MIN_STEP(0x114)  // row_shr:4
  DPP_MIN_STEP(0x118)  // row_shr:8
  DPP_MIN_STEP(0x142)  // row_bcast15
  DPP_MIN_STEP(0x143)  // row_bcast31
#undef DPP_MIN_STEP
  union { double d; int i[2]; } r;
  r.i[0] = __builtin_amdgcn_readlane(u.i[0], 63);
  r.i[1] = __builtin_amdgcn_readlane(u.i[1], 63);
  return r.d;
}

// ---- wave-wide fp32 min via DPP (round-14..16 verified) ----
__device__ __forceinline__ float wave_min_f32(float x) {
  float t;
#define DPP_MINF_STEP(ctrl)                                                  \
  t = __uint_as_float(__builtin_amdgcn_update_dpp(                           \
      (int)__float_as_uint(x), (int)__float_as_uint(x), ctrl, 0xf, 0xf, false));\
  x = fminf(x, t);
  DPP_MINF_STEP(0x111)
  DPP_MINF_STEP(0x112)
  DPP_MINF_STEP(0x114)
  DPP_MINF_STEP(0x118)
  DPP_MINF_STEP(0x142)
  DPP_MINF_STEP(0x143)
#undef DPP_MINF_STEP
  return __uint_as_float(__builtin_amdgcn_readlane((int)__float_as_uint(x), 63));
}

// ---- f64 broadcast-read of one lane's value (uniform index) ----
__device__ __forceinline__ double readlane_f64(double x, int l) {
  union { double d; int i2[2]; } a, b;
  a.d = x;
  b.i2[0] = __builtin_amdgcn_readlane(a.i2[0], l);
  b.i2[1] = __builtin_amdgcn_readlane(a.i2[1], l);
  return b.d;
}

// ---------------- fused pre-pass: split-bf16 pack of X, W1^T, W2^T ----------
__global__ __launch_bounds__(256) void convert_all(
    const float* __restrict__ X, u16* __restrict__ Xh, u16* __restrict__ Xl,
    const float* __restrict__ W1, u16* __restrict__ W1h, u16* __restrict__ W1l,
    const float* __restrict__ W2, u16* __restrict__ W2h, u16* __restrict__ W2l) {
  int b = blockIdx.x, t = threadIdx.x;
  if (b < 1600) {
    int mt = b >> 5, k0b = b & 31;
    size_t outbase = (size_t)b * 4096;
#pragma unroll
    for (int it = 0; it < 2; ++it) {
      int idx = t + it * 256;
      int m = idx & 127, kg = idx >> 7;
      const float* src = X + (size_t)(mt * 128 + m) * FDIM + k0b * 32 + kg * 8;
      float4 v0 = *(const float4*)src;
      float4 v1 = *(const float4*)(src + 4);
      float f[8] = {v0.x, v0.y, v0.z, v0.w, v1.x, v1.y, v1.z, v1.w};
      unsigned short h[8], l[8];
#pragma unroll
      for (int j = 0; j < 8; ++j) {
        h[j] = f32_to_bf16(f[j]);
        l[j] = f32_to_bf16(f[j] - bf16_to_f32(h[j]));
      }
      uint4 hv, lv;
      hv.x = h[0] | ((unsigned)h[1] << 16); hv.y = h[2] | ((unsigned)h[3] << 16);
      hv.z = h[4] | ((unsigned)h[5] << 16); hv.w = h[6] | ((unsigned)h[7] << 16);
      lv.x = l[0] | ((unsigned)l[1] << 16); lv.y = l[2] | ((unsigned)l[3] << 16);
      lv.z = l[4] | ((unsigned)l[5] << 16); lv.w = l[6] | ((unsigned)l[7] << 16);
      size_t off = outbase + (size_t)(kg * 128 + m) * 8;
      *(uint4*)&Xh[off] = hv;
      *(uint4*)&Xl[off] = lv;
    }
  } else if (b < 2624) {
    int bx = b - 1600;
    int nt = bx >> 5, k0b = bx & 31;
    size_t outbase = (size_t)bx * 4096;
#pragma unroll
    for (int it = 0; it < 2; ++it) {
      int idx = t + it * 256;
      int n = idx & 127, kg = idx >> 7;
      float f[8];
#pragma unroll
      for (int j = 0; j < 8; ++j)
        f[j] = W1[(size_t)(k0b * 32 + kg * 8 + j) * HDIM + nt * 128 + n];
      unsigned short h[8], l[8];
#pragma unroll
      for (int j = 0; j < 8; ++j) {
        h[j] = f32_to_bf16(f[j]);
        l[j] = f32_to_bf16(f[j] - bf16_to_f32(h[j]));
      }
      uint4 hv, lv;
      hv.x = h[0] | ((unsigned)h[1] << 16); hv.y = h[2] | ((unsigned)h[3] << 16);
      hv.z = h[4] | ((unsigned)h[5] << 16); hv.w = h[6] | ((unsigned)h[7] << 16);
      lv.x = l[0] | ((unsigned)l[1] << 16); lv.y = l[2] | ((unsigned)l[3] << 16);
      lv.z = l[4] | ((unsigned)l[5] << 16); lv.w = l[6] | ((unsigned)l[7] << 16);
      size_t off = outbase + (size_t)(kg * 128 + n) * 8;
      *(uint4*)&W1h[off] = hv;
      *(uint4*)&W1l[off] = lv;
    }
  } else {
    int idx = (b - 2624) * 256 + t;           // 64*4096 elems
    int n = idx >> 12, k = idx & 4095;
    float f = (n < NMAT) ? W2[(size_t)k * NMAT + n] : 0.0f;
    unsigned short hi = f32_to_bf16(f);
    unsigned short lo = f32_to_bf16(f - bf16_to_f32(hi));
    W2h[idx] = hi;
    W2l[idx] = lo;
  }
}

// ---------------- GEMM1 (split-bf16 MFMA): h = leaky(x @ W1 + b1) -----------
// 128x128 tile, BK=32, 4 waves, 48 MFMA per k-step; staging via
// global_load_lds width-16 only. Epilogue: TRANSPOSED uint4 stores
// (round-12/15/16-verified).
__global__ __launch_bounds__(256) void gemm1_mfma(
    const u16* __restrict__ Ah_, const u16* __restrict__ Al_,
    const u16* __restrict__ Bh_, const u16* __restrict__ Bl_,
    const float* __restrict__ b1,
    u32* __restrict__ HTout,           // chunk base [4096][stride] u32-packed
    int mt0, int stride) {             // m-tile offset of chunk; chunk rows
  __shared__ __align__(16) u16 Ah[4096];
  __shared__ __align__(16) u16 Al[4096];
  __shared__ __align__(16) u16 Bh[4096];
  __shared__ __align__(16) u16 Bl[4096];
  int t = threadIdx.x;
  int wave = t >> 6, lane = t & 63;
  int nt = blockIdx.x & 31;      // 4096/128 n-tiles
  int mtl = blockIdx.x >> 5;     // m-tile local to chunk
  int wm = wave >> 1, wn = wave & 1;
  int fr = lane & 15, fg = lane >> 4;

  f32x4 acc[4][4];
#pragma unroll
  for (int i = 0; i < 4; ++i)
#pragma unroll
    for (int j = 0; j < 4; ++j) acc[i][j] = (f32x4){0.f, 0.f, 0.f, 0.f};

  const u16* pAh = Ah_ + (size_t)(mt0 + mtl) * 32 * 4096;
  const u16* pAl = Al_ + (size_t)(mt0 + mtl) * 32 * 4096;
  const u16* pBh = Bh_ + (size_t)nt * 32 * 4096;
  const u16* pBl = Bl_ + (size_t)nt * 32 * 4096;
  int so = wave * 1024 + lane * 8;   // per-lane src offset (elems), call 0
  int ld = wave * 1024;              // wave-uniform LDS dest (elems)

  for (int k0b = 0; k0b < 32; ++k0b) {
    __syncthreads();                 // previous-iter fragment reads done
    size_t sb = (size_t)k0b * 4096;
    gload16(pAh + sb + so,       &Ah[ld]);
    gload16(pAh + sb + so + 512, &Ah[ld + 512]);
    gload16(pAl + sb + so,       &Al[ld]);
    gload16(pAl + sb + so + 512, &Al[ld + 512]);
    gload16(pBh + sb + so,       &Bh[ld]);
    gload16(pBh + sb + so + 512, &Bh[ld + 512]);
    gload16(pBl + sb + so,       &Bl[ld]);
    gload16(pBl + sb + so + 512, &Bl[ld + 512]);
    __syncthreads();                 // vmcnt(0) drained by compiler before barrier
    // ---- fragments + MFMA ----
    bf16x8 ah[4], al[4], bh[4], bl[4];
#pragma unroll
    for (int i = 0; i < 4; ++i) {
      int arow = (fg * 128 + wm * 64 + i * 16 + fr) * 8;
      ah[i] = *(const bf16x8*)&Ah[arow];
      al[i] = *(const bf16x8*)&Al[arow];
      int brow = (fg * 128 + wn * 64 + i * 16 + fr) * 8;
      bh[i] = *(const bf16x8*)&Bh[brow];
      bl[i] = *(const bf16x8*)&Bl[brow];
    }
#pragma unroll
    for (int i = 0; i < 4; ++i)
#pragma unroll
      for (int j = 0; j < 4; ++j)
        acc[i][j] = __builtin_amdgcn_mfma_f32_16x16x32_bf16(ah[i], bh[j], acc[i][j], 0, 0, 0);
#pragma unroll
    for (int i = 0; i < 4; ++i)
#pragma unroll
      for (int j = 0; j < 4; ++j)
        acc[i][j] = __builtin_amdgcn_mfma_f32_16x16x32_bf16(ah[i], bl[j], acc[i][j], 0, 0, 0);
#pragma unroll
    for (int i = 0; i < 4; ++i)
#pragma unroll
      for (int j = 0; j < 4; ++j)
        acc[i][j] = __builtin_amdgcn_mfma_f32_16x16x32_bf16(al[i], bh[j], acc[i][j], 0, 0, 0);
  }

  // Epilogue (transposed, split-bf16-packed store): col=lane&15,
  // row=(lane>>4)*4+reg [m89]. r=0..3 consecutive rows -> one uint4 store.
  int colb = nt * 128 + wn * 64 + fr;
  int rowb = mtl * 128 + wm * 64 + fg * 4;
#pragma unroll
  for (int j = 0; j < 4; ++j) {
    float bias = b1[colb + j * 16];
#pragma unroll
    for (int i = 0; i < 4; ++i) {
      uint4 pk;
      u32* pp = &pk.x;
#pragma unroll
      for (int r = 0; r < 4; ++r) {
        float v = acc[i][j][r] + bias;
        v = v >= 0.0f ? v : 0.01f * v;
        unsigned short hi = f32_to_bf16(v);
        unsigned short lo = f32_to_bf16(v - bf16_to_f32(hi));
        pp[r] = ((u32)hi << 16) | lo;
      }
      *(uint4*)&HTout[(size_t)(colb + j * 16) * stride + rowb + i * 16] = pk;
    }
  }
}

// ---------------- GEMM2 (split-bf16 MFMA, streaming): Mpart = h @ W2 --------
// Round-16 body (NPART=32, K-slice 128, A depth-2 prefetch; 12800 waves).
__global__ __launch_bounds__(64) void gemm2_bf16(
    const u32* __restrict__ hT,       // chunk base [4096][stride] u32-packed
    const u16* __restrict__ W2h,      // [64][4096] bf16 hi plane
    const u16* __restrict__ W2l,      // [64][4096] bf16 lo plane
    float* __restrict__ Mpart,        // [NPART][6400][50] fp32
    int row0, int stride) {
  int lane = threadIdx.x;
  int kz = blockIdx.y;
  int fr = lane & 15, fg = lane >> 4;

  f32x4 acc[4];
#pragma unroll
  for (int nt = 0; nt < 4; ++nt) acc[nt] = (f32x4){0.f, 0.f, 0.f, 0.f};

  const u32* hA = hT + blockIdx.x * 16 + fr;   // this lane's h-row (A row=fr)
  const int kbase = kz * 128;                  // K slice per partial
  u32 hp[8], hn[8];
#pragma unroll
  for (int kk = 0; kk < 8; ++kk)               // A frag: k = k0 + fg*8 + kk
    hp[kk] = hA[(size_t)(kbase + fg * 8 + kk) * stride];
#pragma unroll
  for (int kk = 0; kk < 8; ++kk)
    hn[kk] = hA[(size_t)(kbase + 32 + fg * 8 + kk) * stride];

  for (int ks = 0; ks < 4; ++ks) {
    int k0 = kbase + ks * 32;
    u32 h2[8];
    if (ks < 2) {                              // A prefetch depth-2
#pragma unroll
      for (int kk = 0; kk < 8; ++kk)
        h2[kk] = hA[(size_t)(k0 + 64 + fg * 8 + kk) * stride];
    }
    short8 hs, ls;
#pragma unroll
    for (int kk = 0; kk < 8; ++kk) {
      hs[kk] = (short)(hp[kk] >> 16);
      ls[kk] = (short)(hp[kk] & 0xffffu);
    }
    bf16x8 ah = *(bf16x8*)&hs;
    bf16x8 al = *(bf16x8*)&ls;
#pragma unroll
    for (int nt = 0; nt < 4; ++nt) {           // B frag: col=fr, k=k0+fg*8..
      const size_t boff = (size_t)(nt * 16 + fr) * 4096 + k0 + fg * 8;
      bf16x8 bh = *(const bf16x8*)&W2h[boff];
      bf16x8 bl = *(const bf16x8*)&W2l[boff];
      acc[nt] = __builtin_amdgcn_mfma_f32_16x16x32_bf16(ah, bh, acc[nt], 0, 0, 0);
      acc[nt] = __builtin_amdgcn_mfma_f32_16x16x32_bf16(ah, bl, acc[nt], 0, 0, 0);
      acc[nt] = __builtin_amdgcn_mfma_f32_16x16x32_bf16(al, bh, acc[nt], 0, 0, 0);
    }
    if (ks < 3) {
#pragma unroll
      for (int kk = 0; kk < 8; ++kk) hp[kk] = hn[kk];
    }
    if (ks < 2) {
#pragma unroll
      for (int kk = 0; kk < 8; ++kk) hn[kk] = h2[kk];
    }
  }

  // D: col=lane&15, row=(lane>>4)*4+reg [m89]
  float* Mout = Mpart + (size_t)kz * PSIZE;
  int rowbase = row0 + blockIdx.x * 16 + fg * 4;
#pragma unroll
  for (int nt = 0; nt < 4; ++nt) {
    int col = nt * 16 + fr;
    if (col < NMAT) {
#pragma unroll
      for (int r = 0; r < 4; ++r)
        Mout[(size_t)(rowbase + r) * NMAT + col] = acc[nt][r];
    }
  }
}

// ---------------- merge: Mmerged[e] = sum_pz (fp64) Mpart[pz][e] ------------
// Full-GPU memory-bound pass (41 MB read ~8 us). Same summation order as the
// previous in-SH merge -> bit-identical. Output into the DEAD hbuf region.
__global__ __launch_bounds__(256) void merge_m(
    const float* __restrict__ Mpart, double* __restrict__ Mmerged) {
  int idx = blockIdx.x * 256 + threadIdx.x;    // grid 1250 -> 320000 elems
  double s = 0.0;
#pragma unroll
  for (int pz = 0; pz < NPART; ++pz)
    s += (double)Mpart[(size_t)pz * PSIZE + idx];
  Mmerged[idx] = s;
}

// ---------------- Fused Sinkhorn + Hungarian (fp64, one wave per batch) -----
// Round-15/16-verified body; round-17: reads pre-merged fp64 M (one load per
// element instead of NPART strided fp32 loads in this latency-bound kernel).
__global__ __launch_bounds__(64) void sinkhorn_hungarian(
    const double* __restrict__ Mm, const float* __restrict__ b2,
    float* __restrict__ out_psi, float* __restrict__ out_X,
    float* __restrict__ out_perms, float* __restrict__ out_dist) {
  int b = blockIdx.x, lane = threadIdx.x;
  __shared__ double P[2500];
  __shared__ double rs[50];
  __shared__ double u[51];
  __shared__ int p[51];
  __shared__ int wayl[51];
  const size_t base = (size_t)b * 2500;

  // ---- Sinkhorn ----
  for (int e = lane; e < 2500; e += 64) {
    double m = Mm[base + e] + (double)b2[e % 50];
    m = m >= 0.0 ? m : 0.01 * m;      // leaky_relu in fp64
    P[e] = exp(m);                    // TAU = 1.0
  }
  __syncthreads();
  for (int it = 0; it < 5; ++it) {
    if (lane < 50) { double s = 0; for (int j = 0; j < 50; ++j) s += P[lane * 50 + j]; rs[lane] = s; }
    __syncthreads();
    for (int e = lane; e < 2500; e += 64) P[e] /= rs[e / 50];   // axis=2
    __syncthreads();
    if (lane < 50) { double s = 0; for (int r = 0; r < 50; ++r) s += P[r * 50 + lane]; rs[lane] = s; }
    __syncthreads();
    for (int e = lane; e < 2500; e += 64) P[e] /= rs[e % 50];   // axis=1
    __syncthreads();
  }
  for (int e = lane; e < 2500; e += 64) {
    float f = (float)P[e];
    out_psi[base + e] = f;
    out_X[base + e] = f;              // ALPHA=1.0 => X == psi exactly
  }
  if (lane < 51) { u[lane] = 0.0; p[lane] = 0; }
  __syncthreads();

  // ---- Hungarian ----
  double v = 0.0;                      // v[lane+1], lane-local (round-7 proven)
  bool lactive = lane < NMAT;
  for (int i = 1; i <= NMAT; ++i) {
    // uniform register caches (all lanes execute these reads; no divergence)
    int pc = (lane <= 50) ? p[lane] : 0;           // p[j] on lane j
    double uc = (lane < 50) ? u[lane + 1] : 0.0;   // u[row] on lane row-1
    bool used = false;
    int way = 0;
    int j0 = 0, j1 = 0;
    double uacc = 0.0, total = 0.0;
    for (int guard = 0; guard < 64; ++guard) {   // defensive cap (normally <=51)
      if (lane == j0 - 1) used = true;           // used[j0] = True (j0>=1)
      int j0u = __builtin_amdgcn_readfirstlane(j0);
      int i0 = (j0u == 0) ? i : __builtin_amdgcn_readlane(pc, j0u);
      double ui0 = readlane_f64(uc, i0 - 1);     // loop-start u (invariant)
      double cand = HINF;
      if (lactive && !used) {
        cand = -P[(i0 - 1) * NMAT + lane] - ui0 - v;   // cost == -P
        way = j0;                                // dead-minv replica
      }
      // f32 fast-path argmin (monotone conversion; exact f64 fixup)
      float cf = (float)cand;
      float mf = wave_min_f32(cf);
      unsigned long long balf = __ballot(cf == mf);
      double m;
      if (__builtin_popcountll(balf) == 1) {     // unique f32 min -> exact
        int lmin = (int)__builtin_ctzll(balf);
        m = readlane_f64(cand, lmin);
        j1 = lmin + 1;
      } else {                                   // rare f32 tie: exact f64 path
        double candt = (cf == mf) ? cand : HINF;
        m = wave_min_f64(candt);
        unsigned long long bal = __ballot(cand == m);
        j1 = (int)__builtin_ctzll(bal) + 1;      // lowest-j among true f64 min
      }
      if (used) { v -= m; uacc += m; }           // v[used]-=d; defer u[p[used]]+=d
      total += m;                                // row i accumulates ALL deltas
      j0 = j1;
      int j1u = __builtin_amdgcn_readfirstlane(j0);
      if (__builtin_amdgcn_readlane(pc, j1u) == 0) break;   // p static in-loop
    }
    // deferred u-scatter: same targets/values as round-7's per-step updates
    if (used && lactive) u[p[lane + 1]] += uacc; // distinct rows (p injective)
    if (lane == 63) u[i] += total;               // virtual col 0: p[0]=i
    if (lactive) wayl[lane + 1] = way;
    __syncthreads();
    if (lane == 0) {                   // augment (serial; path <= 50, bounded)
      int j = j1;
      for (int step = 0; step < 64 && j != 0; ++step) {
        int jw = wayl[j];
        p[j] = (jw == 0) ? i : p[jw];
        j = jw;
      }
    }
    __syncthreads();
  }

  // perms one-hot + dist (fp32 outputs)
  size_t pbase = (size_t)b * 2500;
  for (int e = lane; e < 2500; e += 64) out_perms[pbase + e] = 0.0f;
  __syncthreads();
  double val = 0.0;
  if (lactive) {
    int row = p[lane + 1] - 1;
    if (row < 0) row = 0;              // defensive clamp (provably unreachable)
    if (row > 49) row = 49;
    out_perms[pbase + (size_t)row * NMAT + lane] = 1.0f;
    val = P[(size_t)row * NMAT + lane];
  }
#pragma unroll
  for (int s = 32; s > 0; s >>= 1) val += __shfl_xor(val, s, 64);
  if (lane == 0) out_dist[b] = (float)(val / (double)NMAT);
}

// ---------------------------------------------------------------------------
extern "C" void kernel_launch(void* const* d_in, const int* in_sizes, int n_in,
                              void* d_out, int out_size, void* d_ws, size_t ws_size,
                              hipStream_t stream) {
  const float* x  = (const float*)d_in[0];   // fp32 per the reference dtypes
  const float* W1 = (const float*)d_in[1];
  const float* b1 = (const float*)d_in[2];
  const float* W2 = (const float*)d_in[3];
  const float* b2 = (const float*)d_in[4];
  float* out = (float*)d_out;                // outputs float32 (round-8/11 finding)
  float* out_psi   = out;
  float* out_perms = out + PSIZE;
  float* out_X     = out + 2 * PSIZE;
  float* out_dist  = out + 3 * PSIZE;

  if (ws_size < (size_t)WS_MIN) return;

  char* ws = (char*)d_ws;
  float* Mpart = (float*)(ws + WS_M_OFF);
  u16* Xh  = (u16*)(ws + WS_XH_OFF);
  u16* Xl  = (u16*)(ws + WS_XL_OFF);
  u16* W1h = (u16*)(ws + WS_W1H_OFF);
  u16* W1l = (u16*)(ws + WS_W1L_OFF);
  u16* W2h = (u16*)(ws + WS_W2H_OFF);
  u16* W2l = (u16*)(ws + WS_W2L_OFF);
  u32* hbuf = (u32*)(ws + WS_H_OFF);
  double* Mmerged = (double*)(ws + WS_H_OFF);   // hbuf region is dead by then
  long long avail = (long long)ws_size - WS_H_OFF;
  int max_rows = (int)(avail / (HDIM * 4));
  max_rows = (max_rows / 128) * 128;
  if (max_rows > ROWS) max_rows = ROWS;

  // one-time split-bf16 conversion + packing (fused single launch)
  hipLaunchKernelGGL(convert_all, dim3(3648), dim3(256), 0, stream,
                     x, Xh, Xl, W1, W1h, W1l, W2, W2h, W2l);

  for (int r0 = 0; r0 < ROWS; r0 += max_rows) {
    int rows = (ROWS - r0 < max_rows) ? (ROWS - r0) : max_rows;
    hipLaunchKernelGGL(gemm1_mfma, dim3((rows / 128) * 32), dim3(256), 0, stream,
                       Xh, Xl, W1h, W1l, b1, hbuf, r0 / 128, rows);
    hipLaunchKernelGGL(gemm2_bf16, dim3(rows / 16, NPART), dim3(64), 0, stream,
                       hbuf, W2h, W2l, Mpart, r0, rows);
  }
  // hoisted Mpart merge (full-GPU, HBM-bound) into the dead hbuf region
  hipLaunchKernelGGL(merge_m, dim3(1250), dim3(256), 0, stream, Mpart, Mmerged);
  hipLaunchKernelGGL(sinkhorn_hungarian, dim3(BATCH), dim3(64), 0, stream,
                     Mmerged, b2, out_psi, out_X, out_perms, out_dist);
}

// Round 18
// 450.898 us; speedup vs baseline: 1.0558x; 1.0140x over previous
//
#include <hip/hip_runtime.h>

// Problem constants
#define NMAT 50
#define BATCH 128
#define FDIM 1024
#define HDIM 4096
#define ROWS 6400            // BATCH*NMAT
#define PSIZE 320000         // BATCH*NMAT*NMAT
#define NPART 32             // split-K partials for gemm2
#define HINF 1e18

// ws layout (bytes):
//   Mpart : fp32 [32][6400][50] split-K partials (40.96 MB)
//   Xh/Xl : packed split-bf16 X     [50 mt][32 k0b][4 kg][128 m][8] 13.1 MB each
//   W1h/l : packed split-bf16 W1^T  [32 nt][32 k0b][4 kg][128 n][8] 8.39 MB each
//   W2h/l : bf16 W2^T planes [64][4096] (cols>=50 zero), 512 KB each, L2-resident
//   hbuf  : u32 hT-packed [4096][max_rows]; after gemm2 the region is dead and
//           REUSED for Mmerged fp64 [6400][50] (2.56 MB)
#define WS_M_OFF   0
#define WS_XH_OFF  40960000LL
#define WS_XL_OFF  54067200LL
#define WS_W1H_OFF 67174400LL
#define WS_W1L_OFF 75563008LL
#define WS_W2H_OFF 83951616LL
#define WS_W2L_OFF 84475904LL
#define WS_H_OFF   85000192LL
#define WS_MIN     (WS_H_OFF + 256LL * HDIM * 4)   // ~89.2 MB

typedef __bf16 bf16x8 __attribute__((ext_vector_type(8)));
typedef short short8 __attribute__((ext_vector_type(8)));
typedef float f32x4 __attribute__((ext_vector_type(4)));
typedef unsigned short u16;
typedef unsigned int u32;

__device__ __forceinline__ float bf16_to_f32(unsigned short h) {
  return __uint_as_float(((unsigned int)h) << 16);
}
__device__ __forceinline__ unsigned short f32_to_bf16(float f) {
  unsigned int u = __float_as_uint(f);
  u += 0x7FFFu + ((u >> 16) & 1u);   // RNE
  return (unsigned short)(u >> 16);
}

// async global->LDS, 16B per lane; LDS dest = wave-uniform base + lane*16
__device__ __forceinline__ void gload16(const u16* g, u16* l) {
  __builtin_amdgcn_global_load_lds(
      (const __attribute__((address_space(1))) unsigned int*)g,
      (__attribute__((address_space(3))) unsigned int*)l, 16, 0, 0);
}

// ---- wave-wide fp64 min via DPP (round-5..17 verified) ----
__device__ __forceinline__ double wave_min_f64(double x) {
  union { double d; int i[2]; } u, t;
  u.d = x;
#define DPP_MIN_STEP(ctrl)                                                   \
  t.i[0] = __builtin_amdgcn_update_dpp(u.i[0], u.i[0], ctrl, 0xf, 0xf, false);\
  t.i[1] = __builtin_amdgcn_update_dpp(u.i[1], u.i[1], ctrl, 0xf, 0xf, false);\
  u.d = fmin(u.d, t.d);
  DPP_MIN_STEP(0x111)  // row_shr:1
  DPP_MIN_STEP(0x112)  // row_shr:2
  DPP_MIN_STEP(0x114)  // row_shr:4
  DPP_MIN_STEP(0x118)  // row_shr:8
  DPP_MIN_STEP(0x142)  // row_bcast15
  DPP_MIN_STEP(0x143)  // row_bcast31
#undef DPP_MIN_STEP
  union { double d; int i[2]; } r;
  r.i[0] = __builtin_amdgcn_readlane(u.i[0], 63);
  r.i[1] = __builtin_amdgcn_readlane(u.i[1], 63);
  return r.d;
}

// ---- wave-wide fp32 min via DPP (round-14..17 verified) ----
__device__ __forceinline__ float wave_min_f32(float x) {
  float t;
#define DPP_MINF_STEP(ctrl)                                                  \
  t = __uint_as_float(__builtin_amdgcn_update_dpp(                           \
      (int)__float_as_uint(x), (int)__float_as_uint(x), ctrl, 0xf, 0xf, false));\
  x = fminf(x, t);
  DPP_MINF_STEP(0x111)
  DPP_MINF_STEP(0x112)
  DPP_MINF_STEP(0x114)
  DPP_MINF_STEP(0x118)
  DPP_MINF_STEP(0x142)
  DPP_MINF_STEP(0x143)
#undef DPP_MINF_STEP
  return __uint_as_float(__builtin_amdgcn_readlane((int)__float_as_uint(x), 63));
}

// ---- f64 broadcast-read of one lane's value (uniform index) ----
__device__ __forceinline__ double readlane_f64(double x, int l) {
  union { double d; int i2[2]; } a, b;
  a.d = x;
  b.i2[0] = __builtin_amdgcn_readlane(a.i2[0], l);
  b.i2[1] = __builtin_amdgcn_readlane(a.i2[1], l);
  return b.d;
}

// ---------------- fused pre-pass: split-bf16 pack of X, W1^T, W2^T ----------
__global__ __launch_bounds__(256) void convert_all(
    const float* __restrict__ X, u16* __restrict__ Xh, u16* __restrict__ Xl,
    const float* __restrict__ W1, u16* __restrict__ W1h, u16* __restrict__ W1l,
    const float* __restrict__ W2, u16* __restrict__ W2h, u16* __restrict__ W2l) {
  int b = blockIdx.x, t = threadIdx.x;
  if (b < 1600) {
    int mt = b >> 5, k0b = b & 31;
    size_t outbase = (size_t)b * 4096;
#pragma unroll
    for (int it = 0; it < 2; ++it) {
      int idx = t + it * 256;
      int m = idx & 127, kg = idx >> 7;
      const float* src = X + (size_t)(mt * 128 + m) * FDIM + k0b * 32 + kg * 8;
      float4 v0 = *(const float4*)src;
      float4 v1 = *(const float4*)(src + 4);
      float f[8] = {v0.x, v0.y, v0.z, v0.w, v1.x, v1.y, v1.z, v1.w};
      unsigned short h[8], l[8];
#pragma unroll
      for (int j = 0; j < 8; ++j) {
        h[j] = f32_to_bf16(f[j]);
        l[j] = f32_to_bf16(f[j] - bf16_to_f32(h[j]));
      }
      uint4 hv, lv;
      hv.x = h[0] | ((unsigned)h[1] << 16); hv.y = h[2] | ((unsigned)h[3] << 16);
      hv.z = h[4] | ((unsigned)h[5] << 16); hv.w = h[6] | ((unsigned)h[7] << 16);
      lv.x = l[0] | ((unsigned)l[1] << 16); lv.y = l[2] | ((unsigned)l[3] << 16);
      lv.z = l[4] | ((unsigned)l[5] << 16); lv.w = l[6] | ((unsigned)l[7] << 16);
      size_t off = outbase + (size_t)(kg * 128 + m) * 8;
      *(uint4*)&Xh[off] = hv;
      *(uint4*)&Xl[off] = lv;
    }
  } else if (b < 2624) {
    int bx = b - 1600;
    int nt = bx >> 5, k0b = bx & 31;
    size_t outbase = (size_t)bx * 4096;
#pragma unroll
    for (int it = 0; it < 2; ++it) {
      int idx = t + it * 256;
      int n = idx & 127, kg = idx >> 7;
      float f[8];
#pragma unroll
      for (int j = 0; j < 8; ++j)
        f[j] = W1[(size_t)(k0b * 32 + kg * 8 + j) * HDIM + nt * 128 + n];
      unsigned short h[8], l[8];
#pragma unroll
      for (int j = 0; j < 8; ++j) {
        h[j] = f32_to_bf16(f[j]);
        l[j] = f32_to_bf16(f[j] - bf16_to_f32(h[j]));
      }
      uint4 hv, lv;
      hv.x = h[0] | ((unsigned)h[1] << 16); hv.y = h[2] | ((unsigned)h[3] << 16);
      hv.z = h[4] | ((unsigned)h[5] << 16); hv.w = h[6] | ((unsigned)h[7] << 16);
      lv.x = l[0] | ((unsigned)l[1] << 16); lv.y = l[2] | ((unsigned)l[3] << 16);
      lv.z = l[4] | ((unsigned)l[5] << 16); lv.w = l[6] | ((unsigned)l[7] << 16);
      size_t off = outbase + (size_t)(kg * 128 + n) * 8;
      *(uint4*)&W1h[off] = hv;
      *(uint4*)&W1l[off] = lv;
    }
  } else {
    int idx = (b - 2624) * 256 + t;           // 64*4096 elems
    int n = idx >> 12, k = idx & 4095;
    float f = (n < NMAT) ? W2[(size_t)k * NMAT + n] : 0.0f;
    unsigned short hi = f32_to_bf16(f);
    unsigned short lo = f32_to_bf16(f - bf16_to_f32(hi));
    W2h[idx] = hi;
    W2l[idx] = lo;
  }
}

// ---------------- GEMM1 (split-bf16 MFMA): h = leaky(x @ W1 + b1) -----------
// Round-18: 256x128 tile, BK=32, 8 waves (512 thr), 48 KB LDS (4 planes in
// one buffer: A-hi [0,8K), A-lo [8K,16K), B-hi [16K,20K), B-lo [20K,24K)
// u16 units). Per k-step: 6 gload16/thread (was 8 at 128^2) for 2x FLOP —
// staging and barriers per FLOP halved. Per-call source pointers precomputed
// (k0b enters as uniform +k0b*4096). MFMA order per accumulator unchanged ->
// h bit-identical to round-17. Epilogue: transposed uint4 stores (verified).
__global__ __launch_bounds__(512) void gemm1_mfma(
    const u16* __restrict__ Xh_, const u16* __restrict__ Xl_,
    const u16* __restrict__ W1h_, const u16* __restrict__ W1l_,
    const float* __restrict__ b1,
    u32* __restrict__ HTout,           // chunk base [4096][stride] u32-packed
    int mt0, int stride) {             // 128-tile m offset of chunk; chunk rows
  __shared__ __align__(16) u16 S[24576];   // 48 KB
  int t = threadIdx.x;
  int wave = t >> 6, lane = t & 63;
  int nt = blockIdx.x & 31;      // 4096/128 n-tiles
  int mtl = blockIdx.x >> 5;     // 256-row m-tile local to chunk
  int wm = wave >> 1, wn = wave & 1;   // wm 0..3 (rows), wn 0..1 (cols)
  int fr = lane & 15, fg = lane >> 4;
  int MT0 = mt0 + 2 * mtl;       // first 128-row source tile

  // per-call staging source pointers (lane-dependent; +k0b*4096 per k-step)
  const u16* pre[6];
#pragma unroll
  for (int c = 0; c < 6; ++c) {
    int flat = c * 4096 + t * 8;       // dest u16 offset, also plane decomp
    const u16* base;
    if (flat < 16384) {                // A planes: [kg][256 m][8], 8192 each
      int w = flat & 8191;
      int kg = w >> 11, m = (w >> 3) & 255;
      const u16* plane = (flat < 8192) ? Xh_ : Xl_;
      base = plane + (size_t)((MT0 + (m >> 7)) * 32) * 4096 + kg * 1024 +
             (m & 127) * 8;
    } else {                           // B planes: [kg][128 n][8], 4096 each
      int w = (flat - 16384) & 4095;
      int kg = w >> 10, n = (w >> 3) & 127;
      const u16* plane = (flat < 20480) ? W1h_ : W1l_;
      base = plane + (size_t)(nt * 32) * 4096 + kg * 1024 + n * 8;
    }
    pre[c] = base;
  }
  int ldsb = wave * 512;               // wave-uniform dest base within call

  f32x4 acc[4][4];
#pragma unroll
  for (int i = 0; i < 4; ++i)
#pragma unroll
    for (int j = 0; j < 4; ++j) acc[i][j] = (f32x4){0.f, 0.f, 0.f, 0.f};

  for (int k0b = 0; k0b < 32; ++k0b) {
    __syncthreads();                 // previous-iter fragment reads done
    size_t sb = (size_t)k0b * 4096;
#pragma unroll
    for (int c = 0; c < 6; ++c)
      gload16(pre[c] + sb, &S[c * 4096 + ldsb]);
    __syncthreads();                 // vmcnt(0) drained by compiler before barrier
    // ---- fragments + MFMA ----
    bf16x8 ah[4], al[4], bh[4], bl[4];
#pragma unroll
    for (int i = 0; i < 4; ++i) {
      int arow = fg * 2048 + (wm * 64 + i * 16 + fr) * 8;
      ah[i] = *(const bf16x8*)&S[arow];
      al[i] = *(const bf16x8*)&S[8192 + arow];
      int brow = fg * 1024 + (wn * 64 + i * 16 + fr) * 8;
      bh[i] = *(const bf16x8*)&S[16384 + brow];
      bl[i] = *(const bf16x8*)&S[20480 + brow];
    }
#pragma unroll
    for (int i = 0; i < 4; ++i)
#pragma unroll
      for (int j = 0; j < 4; ++j)
        acc[i][j] = __builtin_amdgcn_mfma_f32_16x16x32_bf16(ah[i], bh[j], acc[i][j], 0, 0, 0);
#pragma unroll
    for (int i = 0; i < 4; ++i)
#pragma unroll
      for (int j = 0; j < 4; ++j)
        acc[i][j] = __builtin_amdgcn_mfma_f32_16x16x32_bf16(ah[i], bl[j], acc[i][j], 0, 0, 0);
#pragma unroll
    for (int i = 0; i < 4; ++i)
#pragma unroll
      for (int j = 0; j < 4; ++j)
        acc[i][j] = __builtin_amdgcn_mfma_f32_16x16x32_bf16(al[i], bh[j], acc[i][j], 0, 0, 0);
  }

  // Epilogue (transposed, split-bf16-packed store): col=lane&15,
  // row=(lane>>4)*4+reg [m89]. r=0..3 consecutive rows -> one uint4 store.
  int colb = nt * 128 + wn * 64 + fr;
  int rowb = mtl * 256 + wm * 64 + fg * 4;
#pragma unroll
  for (int j = 0; j < 4; ++j) {
    float bias = b1[colb + j * 16];
#pragma unroll
    for (int i = 0; i < 4; ++i) {
      uint4 pk;
      u32* pp = &pk.x;
#pragma unroll
      for (int r = 0; r < 4; ++r) {
        float v = acc[i][j][r] + bias;
        v = v >= 0.0f ? v : 0.01f * v;
        unsigned short hi = f32_to_bf16(v);
        unsigned short lo = f32_to_bf16(v - bf16_to_f32(hi));
        pp[r] = ((u32)hi << 16) | lo;
      }
      *(uint4*)&HTout[(size_t)(colb + j * 16) * stride + rowb + i * 16] = pk;
    }
  }
}

// ---------------- GEMM2 (split-bf16 MFMA, streaming): Mpart = h @ W2 --------
// Round-16/17 body (NPART=32, K-slice 128, A depth-2 prefetch; 12800 waves).
__global__ __launch_bounds__(64) void gemm2_bf16(
    const u32* __restrict__ hT,       // chunk base [4096][stride] u32-packed
    const u16* __restrict__ W2h,      // [64][4096] bf16 hi plane
    const u16* __restrict__ W2l,      // [64][4096] bf16 lo plane
    float* __restrict__ Mpart,        // [NPART][6400][50] fp32
    int row0, int stride) {
  int lane = threadIdx.x;
  int kz = blockIdx.y;
  int fr = lane & 15, fg = lane >> 4;

  f32x4 acc[4];
#pragma unroll
  for (int nt = 0; nt < 4; ++nt) acc[nt] = (f32x4){0.f, 0.f, 0.f, 0.f};

  const u32* hA = hT + blockIdx.x * 16 + fr;   // this lane's h-row (A row=fr)
  const int kbase = kz * 128;                  // K slice per partial
  u32 hp[8], hn[8];
#pragma unroll
  for (int kk = 0; kk < 8; ++kk)               // A frag: k = k0 + fg*8 + kk
    hp[kk] = hA[(size_t)(kbase + fg * 8 + kk) * stride];
#pragma unroll
  for (int kk = 0; kk < 8; ++kk)
    hn[kk] = hA[(size_t)(kbase + 32 + fg * 8 + kk) * stride];

  for (int ks = 0; ks < 4; ++ks) {
    int k0 = kbase + ks * 32;
    u32 h2[8];
    if (ks < 2) {                              // A prefetch depth-2
#pragma unroll
      for (int kk = 0; kk < 8; ++kk)
        h2[kk] = hA[(size_t)(k0 + 64 + fg * 8 + kk) * stride];
    }
    short8 hs, ls;
#pragma unroll
    for (int kk = 0; kk < 8; ++kk) {
      hs[kk] = (short)(hp[kk] >> 16);
      ls[kk] = (short)(hp[kk] & 0xffffu);
    }
    bf16x8 ah = *(bf16x8*)&hs;
    bf16x8 al = *(bf16x8*)&ls;
#pragma unroll
    for (int nt = 0; nt < 4; ++nt) {           // B frag: col=fr, k=k0+fg*8..
      const size_t boff = (size_t)(nt * 16 + fr) * 4096 + k0 + fg * 8;
      bf16x8 bh = *(const bf16x8*)&W2h[boff];
      bf16x8 bl = *(const bf16x8*)&W2l[boff];
      acc[nt] = __builtin_amdgcn_mfma_f32_16x16x32_bf16(ah, bh, acc[nt], 0, 0, 0);
      acc[nt] = __builtin_amdgcn_mfma_f32_16x16x32_bf16(ah, bl, acc[nt], 0, 0, 0);
      acc[nt] = __builtin_amdgcn_mfma_f32_16x16x32_bf16(al, bh, acc[nt], 0, 0, 0);
    }
    if (ks < 3) {
#pragma unroll
      for (int kk = 0; kk < 8; ++kk) hp[kk] = hn[kk];
    }
    if (ks < 2) {
#pragma unroll
      for (int kk = 0; kk < 8; ++kk) hn[kk] = h2[kk];
    }
  }

  // D: col=lane&15, row=(lane>>4)*4+reg [m89]
  float* Mout = Mpart + (size_t)kz * PSIZE;
  int rowbase = row0 + blockIdx.x * 16 + fg * 4;
#pragma unroll
  for (int nt = 0; nt < 4; ++nt) {
    int col = nt * 16 + fr;
    if (col < NMAT) {
#pragma unroll
      for (int r = 0; r < 4; ++r)
        Mout[(size_t)(rowbase + r) * NMAT + col] = acc[nt][r];
    }
  }
}

// ---------------- merge: Mmerged[e] = sum_pz (fp64) Mpart[pz][e] ------------
// Full-GPU memory-bound pass (41 MB read ~8 us); same summation order as the
// in-SH merge -> bit-identical. Output into the DEAD hbuf region.
__global__ __launch_bounds__(256) void merge_m(
    const float* __restrict__ Mpart, double* __restrict__ Mmerged) {
  int idx = blockIdx.x * 256 + threadIdx.x;    // grid 1250 -> 320000 elems
  double s = 0.0;
#pragma unroll
  for (int pz = 0; pz < NPART; ++pz)
    s += (double)Mpart[(size_t)pz * PSIZE + idx];
  Mmerged[idx] = s;
}

// ---------------- Fused Sinkhorn + Hungarian (fp64, one wave per batch) -----
// Round-17-verified body (pre-merged fp64 M; register caches; deferred
// u-scatter; f32 fast-path argmin with exact f64 fixup; cost == -P).
__global__ __launch_bounds__(64) void sinkhorn_hungarian(
    const double* __restrict__ Mm, const float* __restrict__ b2,
    float* __restrict__ out_psi, float* __restrict__ out_X,
    float* __restrict__ out_perms, float* __restrict__ out_dist) {
  int b = blockIdx.x, lane = threadIdx.x;
  __shared__ double P[2500];
  __shared__ double rs[50];
  __shared__ double u[51];
  __shared__ int p[51];
  __shared__ int wayl[51];
  const size_t base = (size_t)b * 2500;

  // ---- Sinkhorn ----
  for (int e = lane; e < 2500; e += 64) {
    double m = Mm[base + e] + (double)b2[e % 50];
    m = m >= 0.0 ? m : 0.01 * m;      // leaky_relu in fp64
    P[e] = exp(m);                    // TAU = 1.0
  }
  __syncthreads();
  for (int it = 0; it < 5; ++it) {
    if (lane < 50) { double s = 0; for (int j = 0; j < 50; ++j) s += P[lane * 50 + j]; rs[lane] = s; }
    __syncthreads();
    for (int e = lane; e < 2500; e += 64) P[e] /= rs[e / 50];   // axis=2
    __syncthreads();
    if (lane < 50) { double s = 0; for (int r = 0; r < 50; ++r) s += P[r * 50 + lane]; rs[lane] = s; }
    __syncthreads();
    for (int e = lane; e < 2500; e += 64) P[e] /= rs[e % 50];   // axis=1
    __syncthreads();
  }
  for (int e = lane; e < 2500; e += 64) {
    float f = (float)P[e];
    out_psi[base + e] = f;
    out_X[base + e] = f;              // ALPHA=1.0 => X == psi exactly
  }
  if (lane < 51) { u[lane] = 0.0; p[lane] = 0; }
  __syncthreads();

  // ---- Hungarian ----
  double v = 0.0;                      // v[lane+1], lane-local (round-7 proven)
  bool lactive = lane < NMAT;
  for (int i = 1; i <= NMAT; ++i) {
    int pc = (lane <= 50) ? p[lane] : 0;           // p[j] on lane j
    double uc = (lane < 50) ? u[lane + 1] : 0.0;   // u[row] on lane row-1
    bool used = false;
    int way = 0;
    int j0 = 0, j1 = 0;
    double uacc = 0.0, total = 0.0;
    for (int guard = 0; guard < 64; ++guard) {   // defensive cap (normally <=51)
      if (lane == j0 - 1) used = true;           // used[j0] = True (j0>=1)
      int j0u = __builtin_amdgcn_readfirstlane(j0);
      int i0 = (j0u == 0) ? i : __builtin_amdgcn_readlane(pc, j0u);
      double ui0 = readlane_f64(uc, i0 - 1);     // loop-start u (invariant)
      double cand = HINF;
      if (lactive && !used) {
        cand = -P[(i0 - 1) * NMAT + lane] - ui0 - v;   // cost == -P
        way = j0;                                // dead-minv replica
      }
      // f32 fast-path argmin (monotone conversion; exact f64 fixup)
      float cf = (float)cand;
      float mf = wave_min_f32(cf);
      unsigned long long balf = __ballot(cf == mf);
      double m;
      if (__builtin_popcountll(balf) == 1) {     // unique f32 min -> exact
        int lmin = (int)__builtin_ctzll(balf);
        m = readlane_f64(cand, lmin);
        j1 = lmin + 1;
      } else {                                   // rare f32 tie: exact f64 path
        double candt = (cf == mf) ? cand : HINF;
        m = wave_min_f64(candt);
        unsigned long long bal = __ballot(cand == m);
        j1 = (int)__builtin_ctzll(bal) + 1;      // lowest-j among true f64 min
      }
      if (used) { v -= m; uacc += m; }           // v[used]-=d; defer u[p[used]]+=d
      total += m;                                // row i accumulates ALL deltas
      j0 = j1;
      int j1u = __builtin_amdgcn_readfirstlane(j0);
      if (__builtin_amdgcn_readlane(pc, j1u) == 0) break;   // p static in-loop
    }
    // deferred u-scatter: same targets/values as round-7's per-step updates
    if (used && lactive) u[p[lane + 1]] += uacc; // distinct rows (p injective)
    if (lane == 63) u[i] += total;               // virtual col 0: p[0]=i
    if (lactive) wayl[lane + 1] = way;
    __syncthreads();
    if (lane == 0) {                   // augment (serial; path <= 50, bounded)
      int j = j1;
      for (int step = 0; step < 64 && j != 0; ++step) {
        int jw = wayl[j];
        p[j] = (jw == 0) ? i : p[jw];
        j = jw;
      }
    }
    __syncthreads();
  }

  // perms one-hot + dist (fp32 outputs)
  size_t pbase = (size_t)b * 2500;
  for (int e = lane; e < 2500; e += 64) out_perms[pbase + e] = 0.0f;
  __syncthreads();
  double val = 0.0;
  if (lactive) {
    int row = p[lane + 1] - 1;
    if (row < 0) row = 0;              // defensive clamp (provably unreachable)
    if (row > 49) row = 49;
    out_perms[pbase + (size_t)row * NMAT + lane] = 1.0f;
    val = P[(size_t)row * NMAT + lane];
  }
#pragma unroll
  for (int s = 32; s > 0; s >>= 1) val += __shfl_xor(val, s, 64);
  if (lane == 0) out_dist[b] = (float)(val / (double)NMAT);
}

// ---------------------------------------------------------------------------
extern "C" void kernel_launch(void* const* d_in, const int* in_sizes, int n_in,
                              void* d_out, int out_size, void* d_ws, size_t ws_size,
                              hipStream_t stream) {
  const float* x  = (const float*)d_in[0];   // fp32 per the reference dtypes
  const float* W1 = (const float*)d_in[1];
  const float* b1 = (const float*)d_in[2];
  const float* W2 = (const float*)d_in[3];
  const float* b2 = (const float*)d_in[4];
  float* out = (float*)d_out;                // outputs float32 (round-8/11 finding)
  float* out_psi   = out;
  float* out_perms = out + PSIZE;
  float* out_X     = out + 2 * PSIZE;
  float* out_dist  = out + 3 * PSIZE;

  if (ws_size < (size_t)WS_MIN) return;

  char* ws = (char*)d_ws;
  float* Mpart = (float*)(ws + WS_M_OFF);
  u16* Xh  = (u16*)(ws + WS_XH_OFF);
  u16* Xl  = (u16*)(ws + WS_XL_OFF);
  u16* W1h = (u16*)(ws + WS_W1H_OFF);
  u16* W1l = (u16*)(ws + WS_W1L_OFF);
  u16* W2h = (u16*)(ws + WS_W2H_OFF);
  u16* W2l = (u16*)(ws + WS_W2L_OFF);
  u32* hbuf = (u32*)(ws + WS_H_OFF);
  double* Mmerged = (double*)(ws + WS_H_OFF);   // hbuf region is dead by then
  long long avail = (long long)ws_size - WS_H_OFF;
  int max_rows = (int)(avail / (HDIM * 4));
  max_rows = (max_rows / 256) * 256;            // 256-row m-tiles
  if (max_rows > ROWS) max_rows = ROWS;

  // one-time split-bf16 conversion + packing (fused single launch)
  hipLaunchKernelGGL(convert_all, dim3(3648), dim3(256), 0, stream,
                     x, Xh, Xl, W1, W1h, W1l, W2, W2h, W2l);

  for (int r0 = 0; r0 < ROWS; r0 += max_rows) {
    int rows = (ROWS - r0 < max_rows) ? (ROWS - r0) : max_rows;
    hipLaunchKernelGGL(gemm1_mfma, dim3((rows / 256) * 32), dim3(512), 0, stream,
                       Xh, Xl, W1h, W1l, b1, hbuf, r0 / 128, rows);
    hipLaunchKernelGGL(gemm2_bf16, dim3(rows / 16, NPART), dim3(64), 0, stream,
                       hbuf, W2h, W2l, Mpart, r0, rows);
  }
  // hoisted Mpart merge (full-GPU, HBM-bound) into the dead hbuf region
  hipLaunchKernelGGL(merge_m, dim3(1250), dim3(256), 0, stream, Mpart, Mmerged);
  hipLaunchKernelGGL(sinkhorn_hungarian, dim3(BATCH), dim3(64), 0, stream,
                     Mmerged, b2, out_psi, out_X, out_perms, out_dist);
}